// Round 3
// baseline (1078.220 us; speedup 1.0000x reference)
//
#include <hip/hip_runtime.h>
#include <math.h>

#define NN 50000
#define EE 400000
#define ETOT 450000      // EE + NN self loops
#define CC 64
#define HH 4
#define DEA 16
#define NBATCH 64
#define HC 256           // HH*CC
#define EPSV 1e-5f

__device__ __forceinline__ float4 ld4(const float* p){ return *(const float4*)p; }
__device__ __forceinline__ int rfl(int v){ return __builtin_amdgcn_readfirstlane(v); }

// ---------- edge_attr column sums (for self-loop mean fill) ----------
__global__ void k_easum(const float* __restrict__ ea, float* __restrict__ easum){
  int tid = threadIdx.x;
  int gid = blockIdx.x*256 + tid;
  int gsz = gridDim.x*256;              // 262144, multiple of 16 -> col stable
  float s = 0.f;
  for (long long i = gid; i < (long long)EE*DEA; i += gsz) s += ea[i];
  __shared__ float sd[256];
  sd[tid] = s; __syncthreads();
  if (tid < DEA){
    float t = 0.f;
    for (int j = tid; j < 256; j += DEA) t += sd[j];
    atomicAdd(&easum[tid], t);
  }
}

// ---------- CSR build ----------
__global__ void k_hist(const int* __restrict__ dst, int* __restrict__ cnt){
  int e = blockIdx.x*256 + threadIdx.x;
  if (e < ETOT){
    int d = (e < EE) ? dst[e] : (e - EE);
    atomicAdd(&cnt[d], 1);
  }
}

__global__ void k_scan(int* __restrict__ data, int* __restrict__ row_ptr, int n){
  __shared__ int wsum[16];
  __shared__ int carry_s;
  int tid = threadIdx.x;               // blockDim = 1024
  int lane = tid & 63, wv = tid >> 6;
  if (tid == 0) carry_s = 0;
  __syncthreads();
  for (int base = 0; base < n; base += 1024){
    int i = base + tid;
    int v = (i < n) ? data[i] : 0;
    int incl = v;
    #pragma unroll
    for (int off = 1; off < 64; off <<= 1){
      int t = __shfl_up(incl, off, 64);
      if (lane >= off) incl += t;
    }
    if (lane == 63) wsum[wv] = incl;
    __syncthreads();
    if (wv == 0){
      int s = (lane < 16) ? wsum[lane] : 0;
      #pragma unroll
      for (int off = 1; off < 16; off <<= 1){
        int t = __shfl_up(s, off, 64);
        if (lane >= off) s += t;
      }
      if (lane < 16) wsum[lane] = s;
    }
    __syncthreads();
    int woff = (wv > 0) ? wsum[wv-1] : 0;
    int excl = carry_s + woff + incl - v;
    if (i < n){ row_ptr[i] = excl; data[i] = excl; }
    __syncthreads();
    if (tid == 0) carry_s += wsum[15];
    __syncthreads();
  }
  if (tid == 0) row_ptr[n] = carry_s;
}

__global__ void k_scatter(const int* __restrict__ dst, int* __restrict__ wp, int* __restrict__ col){
  int e = blockIdx.x*256 + threadIdx.x;
  if (e < ETOT){
    int d = (e < EE) ? dst[e] : (e - EE);
    int pos = atomicAdd(&wp[d], 1);
    col[pos] = e;
  }
}

// ---------- GraphNorm + ReLU (one block per batch segment; batch is sorted) ----------
__device__ __forceinline__ int lowerb(const int* a, int n, int key){
  int lo = 0, hi = n;
  while (lo < hi){ int mid = (lo+hi) >> 1; if (a[mid] < key) lo = mid+1; else hi = mid; }
  return lo;
}

__global__ __launch_bounds__(256)
void k_norm(const float* __restrict__ x, const int* __restrict__ batch,
            const float* __restrict__ w, const float* __restrict__ b,
            const float* __restrict__ ms, float* __restrict__ h){
  __shared__ int sb[2];
  __shared__ float red[4][64];
  __shared__ float stat[64];
  int tid = threadIdx.x;
  int bb = blockIdx.x;
  if (tid == 0){ sb[0] = lowerb(batch, NN, bb); sb[1] = lowerb(batch, NN, bb+1); }
  __syncthreads();
  int lo = sb[0], hi = sb[1];
  float inv = 1.0f / fmaxf((float)(hi - lo), 1.0f);
  int c = tid & 63, g = tid >> 6;
  float msv = ms[c];
  float ps = 0.f;
  for (int n = lo+g; n < hi; n += 4) ps += x[(size_t)n*CC + c];
  red[g][c] = ps; __syncthreads();
  if (g == 0) stat[c] = (red[0][c]+red[1][c]+red[2][c]+red[3][c]) * inv;
  __syncthreads();
  float mean = stat[c];
  float pv = 0.f;
  for (int n = lo+g; n < hi; n += 4){ float s = x[(size_t)n*CC+c] - msv*mean; pv += s*s; }
  red[g][c] = pv; __syncthreads();
  if (g == 0) stat[c] = rsqrtf((red[0][c]+red[1][c]+red[2][c]+red[3][c])*inv + EPSV);
  __syncthreads();
  float rstd = stat[c];
  float wv = w[c], bv = b[c];
  for (int n = lo+g; n < hi; n += 4){
    float s = x[(size_t)n*CC+c] - msv*mean;
    float v = s*rstd*wv + bv;
    h[(size_t)n*CC+c] = fmaxf(v, 0.f);
  }
}

// ---------- GEMM: [N,64] @ [64,256] -> [N,256], two weight matrices via blockIdx.z ----------
__global__ __launch_bounds__(256)
void k_gemm(const float* __restrict__ h, const float* __restrict__ WA, const float* __restrict__ WB,
            float* __restrict__ outA, float* __restrict__ outB){
  const float* W = blockIdx.z ? WB : WA;
  float* out = blockIdx.z ? outB : outA;
  int n0 = blockIdx.x * 32;
  int c0 = blockIdx.y * 128;
  __shared__ float hT[64][40];     // transposed h tile, stride 40 (16B-aligned rows)
  __shared__ float Ws[64][128];
  int tid = threadIdx.x;
  for (int t = tid; t < 512; t += 256){
    int r = t >> 4, ch = t & 15;
    int n = n0 + r;
    float4 v = (n < NN) ? ld4(h + (size_t)n*CC + ch*4) : make_float4(0.f,0.f,0.f,0.f);
    hT[ch*4+0][r] = v.x; hT[ch*4+1][r] = v.y; hT[ch*4+2][r] = v.z; hT[ch*4+3][r] = v.w;
  }
  for (int t = tid; t < 2048; t += 256){
    int k = t >> 5, ch = t & 31;
    float4 v = ld4(W + (size_t)k*HC + c0 + ch*4);
    *(float4*)&Ws[k][ch*4] = v;
  }
  __syncthreads();
  int rIdx = tid >> 5, cIdx = tid & 31;
  int r0 = rIdx*4, cc0 = cIdx*4;
  float acc[4][4] = {{0.f}};
  #pragma unroll 8
  for (int k = 0; k < 64; k++){
    float4 a = *(const float4*)&hT[k][r0];
    float4 bq = *(const float4*)&Ws[k][cc0];
    acc[0][0] += a.x*bq.x; acc[0][1] += a.x*bq.y; acc[0][2] += a.x*bq.z; acc[0][3] += a.x*bq.w;
    acc[1][0] += a.y*bq.x; acc[1][1] += a.y*bq.y; acc[1][2] += a.y*bq.z; acc[1][3] += a.y*bq.w;
    acc[2][0] += a.z*bq.x; acc[2][1] += a.z*bq.y; acc[2][2] += a.z*bq.z; acc[2][3] += a.z*bq.w;
    acc[3][0] += a.w*bq.x; acc[3][1] += a.w*bq.y; acc[3][2] += a.w*bq.z; acc[3][3] += a.w*bq.w;
  }
  #pragma unroll
  for (int i = 0; i < 4; i++){
    int n = n0 + r0 + i;
    if (n < NN){
      float4 o = make_float4(acc[i][0], acc[i][1], acc[i][2], acc[i][3]);
      *(float4*)(out + (size_t)n*HC + c0 + cc0) = o;
    }
  }
}

// ---------- per-edge logits, CSR order: wave per CSR slot, pipelined 1 ahead ----------
// Consecutive waves process consecutive CSR slots -> same-dst xr rows are cache-local.
// Output lg[idx] in CSR order so aggregation reads it sequentially.
__global__ __launch_bounds__(256)
void k_logits(const int* __restrict__ col,
              const int* __restrict__ src, const int* __restrict__ dst,
              const float* __restrict__ xl, const float* __restrict__ xr,
              const float* __restrict__ ea, const float* __restrict__ easum,
              const float* __restrict__ We, const float* __restrict__ att,
              float* __restrict__ lgout){
  int lane = threadIdx.x & 63;
  int gwid = (blockIdx.x*256 + threadIdx.x) >> 6;
  int nw = (gridDim.x*256) >> 6;
  float wer[4][16];
  #pragma unroll
  for (int j = 0; j < 4; j++)
    #pragma unroll
    for (int k = 0; k < 16; k++)
      wer[j][k] = We[(size_t)k*HC + j*64 + lane];
  float attv[4];
  #pragma unroll
  for (int j = 0; j < 4; j++) attv[j] = att[j*64 + lane];
  float ems[16];
  const float invE = 1.0f / (float)EE;
  #pragma unroll
  for (int k = 0; k < 16; k++) ems[k] = easum[k] * invE;
  float selfv[4];
  #pragma unroll
  for (int j = 0; j < 4; j++){
    float t = 0.f;
    #pragma unroll
    for (int k = 0; k < 16; k++) t += ems[k]*wer[j][k];
    selfv[j] = t;
  }

  int idx = gwid;
  if (idx >= ETOT) return;

  // ---- prologue load for idx ----
  int eC = rfl(col[idx]);
  int sC, dC;
  if (eC < EE){ sC = rfl(src[eC]); dC = rfl(dst[eC]); }
  else        { sC = eC - EE; dC = sC; }
  float xlvC[4], xrvC[4], earC[16];
  #pragma unroll
  for (int j = 0; j < 4; j++){
    xlvC[j] = xl[(size_t)sC*HC + j*64 + lane];
    xrvC[j] = xr[(size_t)dC*HC + j*64 + lane];
  }
  if (eC < EE){
    #pragma unroll
    for (int q = 0; q < 4; q++){
      float4 v = ld4(ea + (size_t)eC*DEA + q*4);
      earC[q*4+0]=v.x; earC[q*4+1]=v.y; earC[q*4+2]=v.z; earC[q*4+3]=v.w;
    }
  }

  while (idx < ETOT){
    int idxN = idx + nw;
    // ---- prefetch next slot ----
    int eN = 0, sN = 0, dN = 0;
    float xlvN[4], xrvN[4], earN[16];
    if (idxN < ETOT){
      eN = rfl(col[idxN]);
      if (eN < EE){ sN = rfl(src[eN]); dN = rfl(dst[eN]); }
      else        { sN = eN - EE; dN = sN; }
      #pragma unroll
      for (int j = 0; j < 4; j++){
        xlvN[j] = xl[(size_t)sN*HC + j*64 + lane];
        xrvN[j] = xr[(size_t)dN*HC + j*64 + lane];
      }
      if (eN < EE){
        #pragma unroll
        for (int q = 0; q < 4; q++){
          float4 v = ld4(ea + (size_t)eN*DEA + q*4);
          earN[q*4+0]=v.x; earN[q*4+1]=v.y; earN[q*4+2]=v.z; earN[q*4+3]=v.w;
        }
      }
    }

    // ---- compute current ----
    float p[4];
    if (eC < EE){
      #pragma unroll
      for (int j = 0; j < 4; j++){
        float eev = 0.f;
        #pragma unroll
        for (int k = 0; k < 16; k++) eev += earC[k]*wer[j][k];
        float v = xlvC[j] + xrvC[j] + eev;
        v = (v > 0.f) ? v : 0.2f*v;
        p[j] = v * attv[j];
      }
    } else {
      #pragma unroll
      for (int j = 0; j < 4; j++){
        float v = xlvC[j] + xrvC[j] + selfv[j];
        v = (v > 0.f) ? v : 0.2f*v;
        p[j] = v * attv[j];
      }
    }
    #pragma unroll
    for (int off = 32; off > 0; off >>= 1){
      p[0] += __shfl_xor(p[0], off, 64);
      p[1] += __shfl_xor(p[1], off, 64);
      p[2] += __shfl_xor(p[2], off, 64);
      p[3] += __shfl_xor(p[3], off, 64);
    }
    if (lane == 0){
      float4 o = make_float4(p[0], p[1], p[2], p[3]);
      *(float4*)(lgout + (size_t)idx*4) = o;
    }

    // ---- rotate ----
    idx = idxN;
    eC = eN; sC = sN; dC = dN;
    #pragma unroll
    for (int j = 0; j < 4; j++){ xlvC[j] = xlvN[j]; xrvC[j] = xrvN[j]; }
    #pragma unroll
    for (int k = 0; k < 16; k++) earC[k] = earN[k];
  }
}

// ---------- per-node softmax + aggregation (CSR, sequential lg, prefetched gather) ----------
__global__ __launch_bounds__(256)
void k_aggr(const int* __restrict__ row_ptr, const int* __restrict__ col,
            const int* __restrict__ src, const float* __restrict__ lg,
            const float* __restrict__ xl, const float* __restrict__ bias,
            const float* __restrict__ resid, float* __restrict__ out){
  int lane = threadIdx.x & 63;
  int n = blockIdx.x*4 + (threadIdx.x >> 6);
  if (n >= NN) return;
  int rr0 = row_ptr[n], rr1 = row_ptr[n+1];

  // pass 1: max over lg[rr0:rr1] (coalesced sequential)
  float m0=-3.4e38f, m1=m0, m2=m0, m3=m0;
  for (int idx = rr0 + lane; idx < rr1; idx += 64){
    float4 l = ld4(lg + (size_t)idx*4);
    m0 = fmaxf(m0, l.x); m1 = fmaxf(m1, l.y); m2 = fmaxf(m2, l.z); m3 = fmaxf(m3, l.w);
  }
  #pragma unroll
  for (int off = 32; off > 0; off >>= 1){
    m0 = fmaxf(m0, __shfl_xor(m0, off, 64));
    m1 = fmaxf(m1, __shfl_xor(m1, off, 64));
    m2 = fmaxf(m2, __shfl_xor(m2, off, 64));
    m3 = fmaxf(m3, __shfl_xor(m3, off, 64));
  }
  // pass 2: denom
  float d0=0.f, d1=0.f, d2=0.f, d3=0.f;
  for (int idx = rr0 + lane; idx < rr1; idx += 64){
    float4 l = ld4(lg + (size_t)idx*4);
    d0 += __expf(l.x - m0); d1 += __expf(l.y - m1);
    d2 += __expf(l.z - m2); d3 += __expf(l.w - m3);
  }
  #pragma unroll
  for (int off = 32; off > 0; off >>= 1){
    d0 += __shfl_xor(d0, off, 64); d1 += __shfl_xor(d1, off, 64);
    d2 += __shfl_xor(d2, off, 64); d3 += __shfl_xor(d3, off, 64);
  }
  float i0 = 1.0f/d0, i1 = 1.0f/d1, i2 = 1.0f/d2, i3 = 1.0f/d3;

  // pass 3: weighted gather of xl[src], pipelined 1 edge ahead
  float acc = 0.f;
  int eC = rfl(col[rr0]);
  int sC = (eC < EE) ? rfl(src[eC]) : (eC - EE);
  float4 lC = ld4(lg + (size_t)rr0*4);
  float xlvC[4];
  #pragma unroll
  for (int j = 0; j < 4; j++) xlvC[j] = xl[(size_t)sC*HC + j*64 + lane];

  for (int idx = rr0; idx < rr1; idx++){
    int eN = 0, sN = 0;
    float4 lN = make_float4(0.f,0.f,0.f,0.f);
    float xlvN[4] = {0.f,0.f,0.f,0.f};
    if (idx + 1 < rr1){
      eN = rfl(col[idx+1]);
      sN = (eN < EE) ? rfl(src[eN]) : (eN - EE);
      lN = ld4(lg + (size_t)(idx+1)*4);
      #pragma unroll
      for (int j = 0; j < 4; j++) xlvN[j] = xl[(size_t)sN*HC + j*64 + lane];
    }
    float a0 = __expf(lC.x - m0)*i0;
    float a1 = __expf(lC.y - m1)*i1;
    float a2 = __expf(lC.z - m2)*i2;
    float a3 = __expf(lC.w - m3)*i3;
    acc += a0*xlvC[0] + a1*xlvC[1] + a2*xlvC[2] + a3*xlvC[3];
    eC = eN; sC = sN; lC = lN;
    #pragma unroll
    for (int j = 0; j < 4; j++) xlvC[j] = xlvN[j];
  }
  float val = acc*0.25f + bias[lane];
  if (resid) val += resid[(size_t)n*CC + lane];
  out[(size_t)n*CC + lane] = val;
}

extern "C" void kernel_launch(void* const* d_in, const int* in_sizes, int n_in,
                              void* d_out, int out_size, void* d_ws, size_t ws_size,
                              hipStream_t stream) {
  const float* x     = (const float*)d_in[0];
  const int*   ei    = (const int*)d_in[1];
  const int*   src   = ei;
  const int*   dst   = ei + EE;
  const float* ea    = (const float*)d_in[2];
  const int*   batch = (const int*)d_in[3];
  const float* Wl    = (const float*)d_in[4];
  const float* Wr    = (const float*)d_in[5];
  const float* We    = (const float*)d_in[6];
  const float* att   = (const float*)d_in[7];
  const float* gb    = (const float*)d_in[8];
  const float* gw    = (const float*)d_in[9];
  const float* gnb   = (const float*)d_in[10];
  const float* gms   = (const float*)d_in[11];
  float* out = (float*)d_out;

  char* ws = (char*)d_ws;
  size_t off = 0;
  auto alloc = [&](size_t bytes) -> void* {
    void* p = ws + off; off += (bytes + 255) & ~(size_t)255; return p;
  };
  int*   row_ptr = (int*)alloc((NN+1)*sizeof(int));
  int*   wp      = (int*)alloc(NN*sizeof(int));
  int*   colA    = (int*)alloc((size_t)ETOT*sizeof(int));
  float* easum   = (float*)alloc(64);
  float* hbuf    = (float*)alloc((size_t)NN*CC*sizeof(float));
  float* xl      = (float*)alloc((size_t)NN*HC*sizeof(float));
  float* xr      = (float*)alloc((size_t)NN*HC*sizeof(float));
  float* lgbuf   = (float*)alloc((size_t)ETOT*HH*sizeof(float));
  float* xbuf    = (float*)alloc((size_t)NN*CC*sizeof(float));
  if (off > ws_size) return;   // insufficient workspace -> fail loudly (no launch)

  hipMemsetAsync(wp, 0, NN*sizeof(int), stream);
  hipMemsetAsync(easum, 0, 64, stream);
  k_easum<<<1024, 256, 0, stream>>>(ea, easum);
  k_hist<<<(ETOT+255)/256, 256, 0, stream>>>(dst, wp);
  k_scan<<<1, 1024, 0, stream>>>(wp, row_ptr, NN);
  k_scatter<<<(ETOT+255)/256, 256, 0, stream>>>(dst, wp, colA);

  for (int i = 0; i < 2; i++){
    const float* xin = i ? xbuf : x;
    k_norm<<<NBATCH, 256, 0, stream>>>(xin, batch, gw + i*CC, gnb + i*CC, gms + i*CC, hbuf);
    k_gemm<<<dim3((NN+31)/32, 2, 2), 256, 0, stream>>>(hbuf, Wl + (size_t)i*CC*HC, Wr + (size_t)i*CC*HC, xl, xr);
    k_logits<<<2048, 256, 0, stream>>>(colA, src, dst, xl, xr, ea, easum,
                                       We + (size_t)i*DEA*HC, att + i*HH*CC, lgbuf);
    k_aggr<<<(NN+3)/4, 256, 0, stream>>>(row_ptr, colA, src, lgbuf, xl, gb + i*CC,
                                         i ? x : nullptr, i ? out : xbuf);
  }
}

// Round 4
// 1019.524 us; speedup vs baseline: 1.0576x; 1.0576x over previous
//
#include <hip/hip_runtime.h>
#include <math.h>

#define NN 50000
#define EE 400000
#define ETOT 450000      // EE + NN self loops
#define CC 64
#define HH 4
#define DEA 16
#define NBATCH 64
#define HC 256           // HH*CC
#define EPSV 1e-5f
#define NB 49            // ceil(NN/1024)

typedef unsigned short ushort_t;
typedef unsigned int uint_t;

__device__ __forceinline__ float4 ld4(const float* p){ return *(const float4*)p; }
__device__ __forceinline__ int rfl(int v){ return __builtin_amdgcn_readfirstlane(v); }
__device__ __forceinline__ ushort_t f2b(float f){
  uint_t u = __float_as_uint(f);
  uint_t r = (u + 0x7FFFu + ((u >> 16) & 1u)) >> 16;
  return (ushort_t)r;
}
__device__ __forceinline__ float b2f(ushort_t h){
  return __uint_as_float(((uint_t)h) << 16);
}

// ---------- edge_attr column sums (for self-loop mean fill) ----------
__global__ void k_easum(const float* __restrict__ ea, float* __restrict__ easum){
  int tid = threadIdx.x;
  int gid = blockIdx.x*256 + tid;
  int gsz = gridDim.x*256;              // multiple of 16 -> col stable
  float s = 0.f;
  for (long long i = gid; i < (long long)EE*DEA; i += gsz) s += ea[i];
  __shared__ float sd[256];
  sd[tid] = s; __syncthreads();
  if (tid < DEA){
    float t = 0.f;
    for (int j = tid; j < 256; j += DEA) t += sd[j];
    atomicAdd(&easum[tid], t);
  }
}

// ---------- CSR build ----------
__global__ void k_hist(const int* __restrict__ dst, int* __restrict__ cnt){
  int e = blockIdx.x*256 + threadIdx.x;
  if (e < ETOT){
    int d = (e < EE) ? dst[e] : (e - EE);
    atomicAdd(&cnt[d], 1);
  }
}

__global__ __launch_bounds__(1024)
void k_scan1(const int* __restrict__ cnt, int* __restrict__ loc, int* __restrict__ bsum){
  __shared__ int wsum[16];
  int tid = threadIdx.x, lane = tid & 63, wv = tid >> 6;
  int i = blockIdx.x*1024 + tid;
  int v = (i < NN) ? cnt[i] : 0;
  int incl = v;
  #pragma unroll
  for (int off = 1; off < 64; off <<= 1){
    int t = __shfl_up(incl, off, 64);
    if (lane >= off) incl += t;
  }
  if (lane == 63) wsum[wv] = incl;
  __syncthreads();
  if (wv == 0){
    int s = (lane < 16) ? wsum[lane] : 0;
    #pragma unroll
    for (int off = 1; off < 16; off <<= 1){
      int t = __shfl_up(s, off, 64);
      if (lane >= off) s += t;
    }
    if (lane < 16) wsum[lane] = s;
  }
  __syncthreads();
  int excl = (wv ? wsum[wv-1] : 0) + incl - v;
  if (i < NN) loc[i] = excl;
  if (tid == 1023) bsum[blockIdx.x] = wsum[15];
}

__global__ void k_scan2(int* __restrict__ bsum, int* __restrict__ row_ptr){
  int lane = threadIdx.x;   // 64 threads
  int v = (lane < NB) ? bsum[lane] : 0;
  int incl = v;
  #pragma unroll
  for (int off = 1; off < 64; off <<= 1){
    int t = __shfl_up(incl, off, 64);
    if (lane >= off) incl += t;
  }
  if (lane < NB) bsum[lane] = incl - v;
  if (lane == 63) row_ptr[NN] = incl;
}

__global__ __launch_bounds__(1024)
void k_scan3(const int* __restrict__ loc, const int* __restrict__ bsum,
             int* __restrict__ row_ptr, int* __restrict__ wp){
  int i = blockIdx.x*1024 + threadIdx.x;
  if (i < NN){
    int v = loc[i] + bsum[blockIdx.x];
    row_ptr[i] = v; wp[i] = v;
  }
}

// scatter: epos[e] = CSR slot of edge e; csrc[slot] = src node of that edge
__global__ void k_scatter(const int* __restrict__ dst, const int* __restrict__ src,
                          int* __restrict__ wp, int* __restrict__ epos, int* __restrict__ csrc){
  int e = blockIdx.x*256 + threadIdx.x;
  if (e < ETOT){
    int d, s;
    if (e < EE){ d = dst[e]; s = src[e]; } else { d = e - EE; s = d; }
    int pos = atomicAdd(&wp[d], 1);
    epos[e] = pos;
    csrc[pos] = s;
  }
}

// ---------- GraphNorm + ReLU (one block per batch segment; batch is sorted) ----------
__device__ __forceinline__ int lowerb(const int* a, int n, int key){
  int lo = 0, hi = n;
  while (lo < hi){ int mid = (lo+hi) >> 1; if (a[mid] < key) lo = mid+1; else hi = mid; }
  return lo;
}

__global__ __launch_bounds__(256)
void k_norm(const float* __restrict__ x, const int* __restrict__ batch,
            const float* __restrict__ w, const float* __restrict__ b,
            const float* __restrict__ ms, float* __restrict__ h){
  __shared__ int sb[2];
  __shared__ float red[4][64];
  __shared__ float stat[64];
  int tid = threadIdx.x;
  int bb = blockIdx.x;
  if (tid == 0){ sb[0] = lowerb(batch, NN, bb); sb[1] = lowerb(batch, NN, bb+1); }
  __syncthreads();
  int lo = sb[0], hi = sb[1];
  float inv = 1.0f / fmaxf((float)(hi - lo), 1.0f);
  int c = tid & 63, g = tid >> 6;
  float msv = ms[c];
  float ps = 0.f;
  for (int n = lo+g; n < hi; n += 4) ps += x[(size_t)n*CC + c];
  red[g][c] = ps; __syncthreads();
  if (g == 0) stat[c] = (red[0][c]+red[1][c]+red[2][c]+red[3][c]) * inv;
  __syncthreads();
  float mean = stat[c];
  float pv = 0.f;
  for (int n = lo+g; n < hi; n += 4){ float s = x[(size_t)n*CC+c] - msv*mean; pv += s*s; }
  red[g][c] = pv; __syncthreads();
  if (g == 0) stat[c] = rsqrtf((red[0][c]+red[1][c]+red[2][c]+red[3][c])*inv + EPSV);
  __syncthreads();
  float rstd = stat[c];
  float wv = w[c], bv = b[c];
  for (int n = lo+g; n < hi; n += 4){
    float s = x[(size_t)n*CC+c] - msv*mean;
    float v = s*rstd*wv + bv;
    h[(size_t)n*CC+c] = fmaxf(v, 0.f);
  }
}

// ---------- GEMM: [N,64] @ [64,256] -> bf16 [N,256], two weight matrices ----------
__global__ __launch_bounds__(256)
void k_gemm(const float* __restrict__ h, const float* __restrict__ WA, const float* __restrict__ WB,
            ushort_t* __restrict__ outA, ushort_t* __restrict__ outB){
  const float* W = blockIdx.z ? WB : WA;
  ushort_t* out = blockIdx.z ? outB : outA;
  int n0 = blockIdx.x * 32;
  int c0 = blockIdx.y * 128;
  __shared__ float hT[64][40];     // transposed h tile
  __shared__ float Ws[64][128];
  int tid = threadIdx.x;
  for (int t = tid; t < 512; t += 256){
    int r = t >> 4, ch = t & 15;
    int n = n0 + r;
    float4 v = (n < NN) ? ld4(h + (size_t)n*CC + ch*4) : make_float4(0.f,0.f,0.f,0.f);
    hT[ch*4+0][r] = v.x; hT[ch*4+1][r] = v.y; hT[ch*4+2][r] = v.z; hT[ch*4+3][r] = v.w;
  }
  for (int t = tid; t < 2048; t += 256){
    int k = t >> 5, ch = t & 31;
    float4 v = ld4(W + (size_t)k*HC + c0 + ch*4);
    *(float4*)&Ws[k][ch*4] = v;
  }
  __syncthreads();
  int rIdx = tid >> 5, cIdx = tid & 31;
  int r0 = rIdx*4, cc0 = cIdx*4;
  float acc[4][4] = {{0.f}};
  #pragma unroll 8
  for (int k = 0; k < 64; k++){
    float4 a = *(const float4*)&hT[k][r0];
    float4 bq = *(const float4*)&Ws[k][cc0];
    acc[0][0] += a.x*bq.x; acc[0][1] += a.x*bq.y; acc[0][2] += a.x*bq.z; acc[0][3] += a.x*bq.w;
    acc[1][0] += a.y*bq.x; acc[1][1] += a.y*bq.y; acc[1][2] += a.y*bq.z; acc[1][3] += a.y*bq.w;
    acc[2][0] += a.z*bq.x; acc[2][1] += a.z*bq.y; acc[2][2] += a.z*bq.z; acc[2][3] += a.z*bq.w;
    acc[3][0] += a.w*bq.x; acc[3][1] += a.w*bq.y; acc[3][2] += a.w*bq.z; acc[3][3] += a.w*bq.w;
  }
  #pragma unroll
  for (int i = 0; i < 4; i++){
    int n = n0 + r0 + i;
    if (n < NN){
      uint2 o;
      o.x = (uint_t)f2b(acc[i][0]) | ((uint_t)f2b(acc[i][1]) << 16);
      o.y = (uint_t)f2b(acc[i][2]) | ((uint_t)f2b(acc[i][3]) << 16);
      *(uint2*)(out + (size_t)n*HC + c0 + cc0) = o;
    }
  }
}

// ---------- per-edge logits, edge order (sequential src/dst/ea), bf16 gathers ----------
// Writes lg to CSR slot epos[e] so aggregation reads sequentially.
__global__ __launch_bounds__(256)
void k_logits(const ushort_t* __restrict__ xlh, const ushort_t* __restrict__ xrh,
              const int* __restrict__ src, const int* __restrict__ dst,
              const int* __restrict__ epos,
              const float* __restrict__ ea, const float* __restrict__ easum,
              const float* __restrict__ We, const float* __restrict__ att,
              float* __restrict__ lgout){
  int lane = threadIdx.x & 63;
  int gwid = (blockIdx.x*256 + threadIdx.x) >> 6;
  int nw = (gridDim.x*256) >> 6;
  float wer[4][16];
  #pragma unroll
  for (int j = 0; j < 4; j++)
    #pragma unroll
    for (int k = 0; k < 16; k++)
      wer[j][k] = We[(size_t)k*HC + j*64 + lane];
  float attv[4];
  #pragma unroll
  for (int j = 0; j < 4; j++) attv[j] = att[j*64 + lane];
  float selfv[4];
  {
    const float invE = 1.0f / (float)EE;
    #pragma unroll
    for (int j = 0; j < 4; j++){
      float t = 0.f;
      #pragma unroll
      for (int k = 0; k < 16; k++) t += (easum[k]*invE)*wer[j][k];
      selfv[j] = t;
    }
  }

  int e = gwid;
  if (e >= ETOT) return;

  // ---- prologue: stage for edge e ----
  int sC, dC, posC;
  if (e < EE){ sC = rfl(src[e]); dC = rfl(dst[e]); } else { sC = e - EE; dC = sC; }
  posC = rfl(epos[e]);
  ushort_t xlC[4], xrC[4]; float earC[16];
  #pragma unroll
  for (int j = 0; j < 4; j++){
    xlC[j] = xlh[(size_t)sC*HC + j*64 + lane];
    xrC[j] = xrh[(size_t)dC*HC + j*64 + lane];
  }
  if (e < EE){
    #pragma unroll
    for (int q = 0; q < 4; q++){
      float4 v = ld4(ea + (size_t)e*DEA + q*4);
      earC[q*4+0]=v.x; earC[q*4+1]=v.y; earC[q*4+2]=v.z; earC[q*4+3]=v.w;
    }
  }

  while (e < ETOT){
    int eN = e + nw;
    // ---- prefetch next edge ----
    int sN = 0, dN = 0, posN = 0;
    ushort_t xlN[4] = {0,0,0,0}, xrN[4] = {0,0,0,0};
    float earN[16];
    if (eN < ETOT){
      if (eN < EE){ sN = rfl(src[eN]); dN = rfl(dst[eN]); } else { sN = eN - EE; dN = sN; }
      posN = rfl(epos[eN]);
      #pragma unroll
      for (int j = 0; j < 4; j++){
        xlN[j] = xlh[(size_t)sN*HC + j*64 + lane];
        xrN[j] = xrh[(size_t)dN*HC + j*64 + lane];
      }
      if (eN < EE){
        #pragma unroll
        for (int q = 0; q < 4; q++){
          float4 v = ld4(ea + (size_t)eN*DEA + q*4);
          earN[q*4+0]=v.x; earN[q*4+1]=v.y; earN[q*4+2]=v.z; earN[q*4+3]=v.w;
        }
      }
    }

    // ---- compute current edge ----
    float p[4];
    if (e < EE){
      #pragma unroll
      for (int j = 0; j < 4; j++){
        float eev = 0.f;
        #pragma unroll
        for (int k = 0; k < 16; k++) eev += earC[k]*wer[j][k];
        float v = b2f(xlC[j]) + b2f(xrC[j]) + eev;
        v = (v > 0.f) ? v : 0.2f*v;
        p[j] = v * attv[j];
      }
    } else {
      #pragma unroll
      for (int j = 0; j < 4; j++){
        float v = b2f(xlC[j]) + b2f(xrC[j]) + selfv[j];
        v = (v > 0.f) ? v : 0.2f*v;
        p[j] = v * attv[j];
      }
    }
    #pragma unroll
    for (int off = 32; off > 0; off >>= 1){
      p[0] += __shfl_xor(p[0], off, 64);
      p[1] += __shfl_xor(p[1], off, 64);
      p[2] += __shfl_xor(p[2], off, 64);
      p[3] += __shfl_xor(p[3], off, 64);
    }
    if (lane == 0){
      float4 o = make_float4(p[0], p[1], p[2], p[3]);
      *(float4*)(lgout + (size_t)posC*4) = o;
    }

    // ---- rotate ----
    e = eN; sC = sN; dC = dN; posC = posN;
    #pragma unroll
    for (int j = 0; j < 4; j++){ xlC[j] = xlN[j]; xrC[j] = xrN[j]; }
    #pragma unroll
    for (int k = 0; k < 16; k++) earC[k] = earN[k];
  }
}

// ---------- per-node softmax + aggregation: sequential lg/csrc, bf16 gather ----------
__global__ __launch_bounds__(256)
void k_aggr(const int* __restrict__ row_ptr, const int* __restrict__ csrc,
            const float* __restrict__ lg, const ushort_t* __restrict__ xlh,
            const float* __restrict__ bias, const float* __restrict__ resid,
            float* __restrict__ out){
  int lane = threadIdx.x & 63;
  int n = blockIdx.x*4 + (threadIdx.x >> 6);
  if (n >= NN) return;
  int rr0 = row_ptr[n], rr1 = row_ptr[n+1];

  // pass 1: max (sequential lg)
  float m0=-3.4e38f, m1=m0, m2=m0, m3=m0;
  for (int idx = rr0 + lane; idx < rr1; idx += 64){
    float4 l = ld4(lg + (size_t)idx*4);
    m0 = fmaxf(m0, l.x); m1 = fmaxf(m1, l.y); m2 = fmaxf(m2, l.z); m3 = fmaxf(m3, l.w);
  }
  #pragma unroll
  for (int off = 32; off > 0; off >>= 1){
    m0 = fmaxf(m0, __shfl_xor(m0, off, 64));
    m1 = fmaxf(m1, __shfl_xor(m1, off, 64));
    m2 = fmaxf(m2, __shfl_xor(m2, off, 64));
    m3 = fmaxf(m3, __shfl_xor(m3, off, 64));
  }
  // pass 2: denom
  float d0=0.f, d1=0.f, d2=0.f, d3=0.f;
  for (int idx = rr0 + lane; idx < rr1; idx += 64){
    float4 l = ld4(lg + (size_t)idx*4);
    d0 += __expf(l.x - m0); d1 += __expf(l.y - m1);
    d2 += __expf(l.z - m2); d3 += __expf(l.w - m3);
  }
  #pragma unroll
  for (int off = 32; off > 0; off >>= 1){
    d0 += __shfl_xor(d0, off, 64); d1 += __shfl_xor(d1, off, 64);
    d2 += __shfl_xor(d2, off, 64); d3 += __shfl_xor(d3, off, 64);
  }
  float i0 = 1.0f/d0, i1 = 1.0f/d1, i2 = 1.0f/d2, i3 = 1.0f/d3;

  // pass 3: weighted bf16 gather, pipelined 1 ahead
  float acc = 0.f;
  int sC = rfl(csrc[rr0]);
  float4 lC = ld4(lg + (size_t)rr0*4);
  ushort_t xa[4];
  #pragma unroll
  for (int j = 0; j < 4; j++) xa[j] = xlh[(size_t)sC*HC + j*64 + lane];

  for (int idx = rr0; idx < rr1; idx++){
    int sN = 0;
    float4 lN = make_float4(0.f,0.f,0.f,0.f);
    ushort_t xb[4] = {0,0,0,0};
    if (idx + 1 < rr1){
      sN = rfl(csrc[idx+1]);
      lN = ld4(lg + (size_t)(idx+1)*4);
      #pragma unroll
      for (int j = 0; j < 4; j++) xb[j] = xlh[(size_t)sN*HC + j*64 + lane];
    }
    float a0 = __expf(lC.x - m0)*i0;
    float a1 = __expf(lC.y - m1)*i1;
    float a2 = __expf(lC.z - m2)*i2;
    float a3 = __expf(lC.w - m3)*i3;
    acc += a0*b2f(xa[0]) + a1*b2f(xa[1]) + a2*b2f(xa[2]) + a3*b2f(xa[3]);
    sC = sN; lC = lN;
    #pragma unroll
    for (int j = 0; j < 4; j++) xa[j] = xb[j];
  }
  float val = acc*0.25f + bias[lane];
  if (resid) val += resid[(size_t)n*CC + lane];
  out[(size_t)n*CC + lane] = val;
}

extern "C" void kernel_launch(void* const* d_in, const int* in_sizes, int n_in,
                              void* d_out, int out_size, void* d_ws, size_t ws_size,
                              hipStream_t stream) {
  const float* x     = (const float*)d_in[0];
  const int*   ei    = (const int*)d_in[1];
  const int*   src   = ei;
  const int*   dst   = ei + EE;
  const float* ea    = (const float*)d_in[2];
  const int*   batch = (const int*)d_in[3];
  const float* Wl    = (const float*)d_in[4];
  const float* Wr    = (const float*)d_in[5];
  const float* We    = (const float*)d_in[6];
  const float* att   = (const float*)d_in[7];
  const float* gb    = (const float*)d_in[8];
  const float* gw    = (const float*)d_in[9];
  const float* gnb   = (const float*)d_in[10];
  const float* gms   = (const float*)d_in[11];
  float* out = (float*)d_out;

  char* ws = (char*)d_ws;
  size_t off = 0;
  auto alloc = [&](size_t bytes) -> void* {
    void* p = ws + off; off += (bytes + 255) & ~(size_t)255; return p;
  };
  int*   cnt     = (int*)alloc(NN*sizeof(int));
  int*   loc     = (int*)alloc(NN*sizeof(int));
  int*   bsum    = (int*)alloc(64*sizeof(int));
  int*   wp      = (int*)alloc(NN*sizeof(int));
  int*   row_ptr = (int*)alloc((NN+1)*sizeof(int));
  int*   epos    = (int*)alloc((size_t)ETOT*sizeof(int));
  int*   csrc    = (int*)alloc((size_t)ETOT*sizeof(int));
  float* easum   = (float*)alloc(64);
  float* hbuf    = (float*)alloc((size_t)NN*CC*sizeof(float));
  ushort_t* xlh  = (ushort_t*)alloc((size_t)NN*HC*sizeof(ushort_t));
  ushort_t* xrh  = (ushort_t*)alloc((size_t)NN*HC*sizeof(ushort_t));
  float* lgbuf   = (float*)alloc((size_t)ETOT*HH*sizeof(float));
  float* xbuf    = (float*)alloc((size_t)NN*CC*sizeof(float));
  if (off > ws_size) return;   // insufficient workspace -> fail loudly (no launch)

  hipMemsetAsync(cnt, 0, NN*sizeof(int), stream);
  hipMemsetAsync(easum, 0, 64, stream);
  k_easum<<<1024, 256, 0, stream>>>(ea, easum);
  k_hist<<<(ETOT+255)/256, 256, 0, stream>>>(dst, cnt);
  k_scan1<<<NB, 1024, 0, stream>>>(cnt, loc, bsum);
  k_scan2<<<1, 64, 0, stream>>>(bsum, row_ptr);
  k_scan3<<<NB, 1024, 0, stream>>>(loc, bsum, row_ptr, wp);
  k_scatter<<<(ETOT+255)/256, 256, 0, stream>>>(dst, src, wp, epos, csrc);

  for (int i = 0; i < 2; i++){
    const float* xin = i ? xbuf : x;
    k_norm<<<NBATCH, 256, 0, stream>>>(xin, batch, gw + i*CC, gnb + i*CC, gms + i*CC, hbuf);
    k_gemm<<<dim3((NN+31)/32, 2, 2), 256, 0, stream>>>(hbuf, Wl + (size_t)i*CC*HC, Wr + (size_t)i*CC*HC, xlh, xrh);
    k_logits<<<2048, 256, 0, stream>>>(xlh, xrh, src, dst, epos, ea, easum,
                                       We + (size_t)i*DEA*HC, att + i*HH*CC, lgbuf);
    k_aggr<<<(NN+3)/4, 256, 0, stream>>>(row_ptr, csrc, lgbuf, xlh, gb + i*CC,
                                         i ? x : nullptr, i ? out : xbuf);
  }
}

// Round 5
// 1004.453 us; speedup vs baseline: 1.0734x; 1.0150x over previous
//
#include <hip/hip_runtime.h>
#include <math.h>

#define NN 50000
#define EE 400000
#define ETOT 450000      // EE + NN self loops
#define CC 64
#define HH 4
#define DEA 16
#define NBATCH 64
#define HC 256           // HH*CC
#define EPSV 1e-5f
#define NB 49            // ceil(NN/1024)
#define NGB 782          // ceil(NN/64)

typedef unsigned short ushort_t;
typedef unsigned int uint_t;

__device__ __forceinline__ float4 ld4(const float* p){ return *(const float4*)p; }
__device__ __forceinline__ int rfl(int v){ return __builtin_amdgcn_readfirstlane(v); }
__device__ __forceinline__ ushort_t f2b(float f){
  uint_t u = __float_as_uint(f);
  uint_t r = (u + 0x7FFFu + ((u >> 16) & 1u)) >> 16;
  return (ushort_t)r;
}
// packed-pair bf16 -> float: low half / high half of a uint
__device__ __forceinline__ float b2f_lo(uint_t u){ return __uint_as_float(u << 16); }
__device__ __forceinline__ float b2f_hi(uint_t u){ return __uint_as_float(u & 0xFFFF0000u); }

// ---------- edge_attr column sums (for self-loop mean fill) ----------
__global__ void k_easum(const float* __restrict__ ea, float* __restrict__ easum){
  int tid = threadIdx.x;
  int gid = blockIdx.x*256 + tid;
  int gsz = gridDim.x*256;              // multiple of 16 -> col stable
  float s = 0.f;
  for (long long i = gid; i < (long long)EE*DEA; i += gsz) s += ea[i];
  __shared__ float sd[256];
  sd[tid] = s; __syncthreads();
  if (tid < DEA){
    float t = 0.f;
    for (int j = tid; j < 256; j += DEA) t += sd[j];
    atomicAdd(&easum[tid], t);
  }
}

// ---------- CSR build ----------
__global__ void k_hist(const int* __restrict__ dst, int* __restrict__ cnt){
  int e = blockIdx.x*256 + threadIdx.x;
  if (e < ETOT){
    int d = (e < EE) ? dst[e] : (e - EE);
    atomicAdd(&cnt[d], 1);
  }
}

__global__ __launch_bounds__(1024)
void k_scan1(const int* __restrict__ cnt, int* __restrict__ loc, int* __restrict__ bsum){
  __shared__ int wsum[16];
  int tid = threadIdx.x, lane = tid & 63, wv = tid >> 6;
  int i = blockIdx.x*1024 + tid;
  int v = (i < NN) ? cnt[i] : 0;
  int incl = v;
  #pragma unroll
  for (int off = 1; off < 64; off <<= 1){
    int t = __shfl_up(incl, off, 64);
    if (lane >= off) incl += t;
  }
  if (lane == 63) wsum[wv] = incl;
  __syncthreads();
  if (wv == 0){
    int s = (lane < 16) ? wsum[lane] : 0;
    #pragma unroll
    for (int off = 1; off < 16; off <<= 1){
      int t = __shfl_up(s, off, 64);
      if (lane >= off) s += t;
    }
    if (lane < 16) wsum[lane] = s;
  }
  __syncthreads();
  int excl = (wv ? wsum[wv-1] : 0) + incl - v;
  if (i < NN) loc[i] = excl;
  if (tid == 1023) bsum[blockIdx.x] = wsum[15];
}

__global__ void k_scan2(int* __restrict__ bsum, int* __restrict__ row_ptr){
  int lane = threadIdx.x;   // 64 threads
  int v = (lane < NB) ? bsum[lane] : 0;
  int incl = v;
  #pragma unroll
  for (int off = 1; off < 64; off <<= 1){
    int t = __shfl_up(incl, off, 64);
    if (lane >= off) incl += t;
  }
  if (lane < NB) bsum[lane] = incl - v;
  if (lane == 63) row_ptr[NN] = incl;
}

__global__ __launch_bounds__(1024)
void k_scan3(const int* __restrict__ loc, const int* __restrict__ bsum,
             int* __restrict__ row_ptr, int* __restrict__ wp){
  int i = blockIdx.x*1024 + threadIdx.x;
  if (i < NN){
    int v = loc[i] + bsum[blockIdx.x];
    row_ptr[i] = v; wp[i] = v;
  }
}

// scatter: epos[e] = CSR slot of edge e; csrc[slot] = src node of that edge
__global__ void k_scatter(const int* __restrict__ dst, const int* __restrict__ src,
                          int* __restrict__ wp, int* __restrict__ epos, int* __restrict__ csrc){
  int e = blockIdx.x*256 + threadIdx.x;
  if (e < ETOT){
    int d, s;
    if (e < EE){ d = dst[e]; s = src[e]; } else { d = e - EE; s = d; }
    int pos = atomicAdd(&wp[d], 1);
    epos[e] = pos;
    csrc[pos] = s;
  }
}

// ---------- GraphNorm + ReLU (one block per batch segment; batch is sorted) ----------
__device__ __forceinline__ int lowerb(const int* a, int n, int key){
  int lo = 0, hi = n;
  while (lo < hi){ int mid = (lo+hi) >> 1; if (a[mid] < key) lo = mid+1; else hi = mid; }
  return lo;
}

__global__ __launch_bounds__(256)
void k_norm(const float* __restrict__ x, const int* __restrict__ batch,
            const float* __restrict__ w, const float* __restrict__ b,
            const float* __restrict__ ms, float* __restrict__ h){
  __shared__ int sb[2];
  __shared__ float red[4][64];
  __shared__ float stat[64];
  int tid = threadIdx.x;
  int bb = blockIdx.x;
  if (tid == 0){ sb[0] = lowerb(batch, NN, bb); sb[1] = lowerb(batch, NN, bb+1); }
  __syncthreads();
  int lo = sb[0], hi = sb[1];
  float inv = 1.0f / fmaxf((float)(hi - lo), 1.0f);
  int c = tid & 63, g = tid >> 6;
  float msv = ms[c];
  float ps = 0.f;
  for (int n = lo+g; n < hi; n += 4) ps += x[(size_t)n*CC + c];
  red[g][c] = ps; __syncthreads();
  if (g == 0) stat[c] = (red[0][c]+red[1][c]+red[2][c]+red[3][c]) * inv;
  __syncthreads();
  float mean = stat[c];
  float pv = 0.f;
  for (int n = lo+g; n < hi; n += 4){ float s = x[(size_t)n*CC+c] - msv*mean; pv += s*s; }
  red[g][c] = pv; __syncthreads();
  if (g == 0) stat[c] = rsqrtf((red[0][c]+red[1][c]+red[2][c]+red[3][c])*inv + EPSV);
  __syncthreads();
  float rstd = stat[c];
  float wv = w[c], bv = b[c];
  for (int n = lo+g; n < hi; n += 4){
    float s = x[(size_t)n*CC+c] - msv*mean;
    float v = s*rstd*wv + bv;
    h[(size_t)n*CC+c] = fmaxf(v, 0.f);
  }
}

// ---------- GEMM: [N,64] @ [64,256] -> bf16 packed [n][c*4+h] ----------
// 64-row tile, full 256-col tile. Thread: c = tid&63, rgroup = tid>>6 (16 rows).
// Output element (channel c, head j) stored at n*256 + c*4 + j -> one ushort4/row/lane.
__global__ __launch_bounds__(256)
void k_gemm(const float* __restrict__ h, const float* __restrict__ WA, const float* __restrict__ WB,
            ushort_t* __restrict__ outA, ushort_t* __restrict__ outB){
  const float* W = blockIdx.z ? WB : WA;
  ushort_t* out = blockIdx.z ? outB : outA;
  int n0 = blockIdx.x * 64;
  __shared__ float hT[64][72];      // [k][row]
  __shared__ float Ws[64][256];     // [k][col], col = j*64+c
  int tid = threadIdx.x;
  for (int t = tid; t < 1024; t += 256){      // 64 rows x 16 float4
    int r = t >> 4, ch = t & 15;
    int n = n0 + r;
    float4 v = (n < NN) ? ld4(h + (size_t)n*CC + ch*4) : make_float4(0.f,0.f,0.f,0.f);
    hT[ch*4+0][r] = v.x; hT[ch*4+1][r] = v.y; hT[ch*4+2][r] = v.z; hT[ch*4+3][r] = v.w;
  }
  for (int t = tid; t < 4096; t += 256){      // 64 k x 64 float4
    int k = t >> 6, ch = t & 63;
    float4 v = ld4(W + (size_t)k*HC + ch*4);
    *(float4*)&Ws[k][ch*4] = v;
  }
  __syncthreads();
  int c = tid & 63, rg = tid >> 6;
  int r0 = rg * 16;
  float acc[16][4];
  #pragma unroll
  for (int i = 0; i < 16; i++){ acc[i][0]=0.f; acc[i][1]=0.f; acc[i][2]=0.f; acc[i][3]=0.f; }
  for (int k = 0; k < 64; k++){
    float4 a0 = *(const float4*)&hT[k][r0+0];
    float4 a1 = *(const float4*)&hT[k][r0+4];
    float4 a2 = *(const float4*)&hT[k][r0+8];
    float4 a3 = *(const float4*)&hT[k][r0+12];
    float b0 = Ws[k][c], b1 = Ws[k][c+64], b2 = Ws[k][c+128], b3 = Ws[k][c+192];
    const float av[16] = {a0.x,a0.y,a0.z,a0.w, a1.x,a1.y,a1.z,a1.w,
                          a2.x,a2.y,a2.z,a2.w, a3.x,a3.y,a3.z,a3.w};
    #pragma unroll
    for (int i = 0; i < 16; i++){
      acc[i][0] += av[i]*b0; acc[i][1] += av[i]*b1;
      acc[i][2] += av[i]*b2; acc[i][3] += av[i]*b3;
    }
  }
  #pragma unroll
  for (int i = 0; i < 16; i++){
    int n = n0 + r0 + i;
    if (n < NN){
      uint2 o;
      o.x = (uint_t)f2b(acc[i][0]) | ((uint_t)f2b(acc[i][1]) << 16);
      o.y = (uint_t)f2b(acc[i][2]) | ((uint_t)f2b(acc[i][3]) << 16);
      *(uint2*)(out + (size_t)n*HC + c*4) = o;
    }
  }
}

// ---------- per-edge logits, edge order, packed gathers, scalarized indices ----------
// Two independent edges per iteration (ILP without rotate overhead).
__global__ __launch_bounds__(256)
void k_logits(const ushort_t* __restrict__ xlh, const ushort_t* __restrict__ xrh,
              const int* __restrict__ src, const int* __restrict__ dst,
              const int* __restrict__ epos,
              const float* __restrict__ ea,
              const float* __restrict__ We, const float* __restrict__ att,
              float* __restrict__ lgout){
  int lane = threadIdx.x & 63;
  int gwid = (blockIdx.x*256 + threadIdx.x) >> 6;
  int nw = (gridDim.x*256) >> 6;
  float wer[4][16];
  #pragma unroll
  for (int j = 0; j < 4; j++)
    #pragma unroll
    for (int k = 0; k < 16; k++)
      wer[j][k] = We[(size_t)k*HC + j*64 + lane];
  float attv[4];
  #pragma unroll
  for (int j = 0; j < 4; j++) attv[j] = att[j*64 + lane];

  auto body = [&](int e){
    int eu = rfl(e);
    int s = src[eu], d = dst[eu], pos = epos[eu];   // uniform -> s_load
    uint2 xlp = *(const uint2*)(xlh + (size_t)s*HC + lane*4);
    uint2 xrp = *(const uint2*)(xrh + (size_t)d*HC + lane*4);
    float4 e0 = ld4(ea + (size_t)eu*DEA + 0);
    float4 e1 = ld4(ea + (size_t)eu*DEA + 4);
    float4 e2 = ld4(ea + (size_t)eu*DEA + 8);
    float4 e3 = ld4(ea + (size_t)eu*DEA + 12);
    const float ear[16] = {e0.x,e0.y,e0.z,e0.w, e1.x,e1.y,e1.z,e1.w,
                           e2.x,e2.y,e2.z,e2.w, e3.x,e3.y,e3.z,e3.w};
    float xlf[4] = {b2f_lo(xlp.x), b2f_hi(xlp.x), b2f_lo(xlp.y), b2f_hi(xlp.y)};
    float xrf[4] = {b2f_lo(xrp.x), b2f_hi(xrp.x), b2f_lo(xrp.y), b2f_hi(xrp.y)};
    float p[4];
    #pragma unroll
    for (int j = 0; j < 4; j++){
      float eev = 0.f;
      #pragma unroll
      for (int k = 0; k < 16; k++) eev += ear[k]*wer[j][k];
      float v = xlf[j] + xrf[j] + eev;
      v = (v > 0.f) ? v : 0.2f*v;
      p[j] = v * attv[j];
    }
    #pragma unroll
    for (int off = 32; off > 0; off >>= 1){
      p[0] += __shfl_xor(p[0], off, 64);
      p[1] += __shfl_xor(p[1], off, 64);
      p[2] += __shfl_xor(p[2], off, 64);
      p[3] += __shfl_xor(p[3], off, 64);
    }
    if (lane == 0){
      float4 o = make_float4(p[0], p[1], p[2], p[3]);
      *(float4*)(lgout + (size_t)pos*4) = o;
    }
  };

  for (int e = gwid; e < EE; e += 2*nw){
    body(e);
    int e2 = e + nw;
    if (e2 < EE) body(e2);
  }
}

// ---------- self-loop logits: sequential rows, no gathers ----------
__global__ __launch_bounds__(256)
void k_logits_self(const ushort_t* __restrict__ xlh, const ushort_t* __restrict__ xrh,
                   const int* __restrict__ epos, const float* __restrict__ easum,
                   const float* __restrict__ We, const float* __restrict__ att,
                   float* __restrict__ lgout){
  int lane = threadIdx.x & 63;
  int gwid = (blockIdx.x*256 + threadIdx.x) >> 6;
  int nw = (gridDim.x*256) >> 6;
  float attv[4], selfv[4];
  #pragma unroll
  for (int j = 0; j < 4; j++) attv[j] = att[j*64 + lane];
  {
    const float invE = 1.0f / (float)EE;
    #pragma unroll
    for (int j = 0; j < 4; j++){
      float t = 0.f;
      #pragma unroll
      for (int k = 0; k < 16; k++) t += (easum[k]*invE)*We[(size_t)k*HC + j*64 + lane];
      selfv[j] = t;
    }
  }
  for (int n = gwid; n < NN; n += nw){
    int nu = rfl(n);
    int pos = epos[EE + nu];                 // uniform -> s_load
    uint2 xlp = *(const uint2*)(xlh + (size_t)nu*HC + lane*4);
    uint2 xrp = *(const uint2*)(xrh + (size_t)nu*HC + lane*4);
    float p[4] = {b2f_lo(xlp.x)+b2f_lo(xrp.x)+selfv[0], b2f_hi(xlp.x)+b2f_hi(xrp.x)+selfv[1],
                  b2f_lo(xlp.y)+b2f_lo(xrp.y)+selfv[2], b2f_hi(xlp.y)+b2f_hi(xrp.y)+selfv[3]};
    #pragma unroll
    for (int j = 0; j < 4; j++){
      float v = p[j];
      v = (v > 0.f) ? v : 0.2f*v;
      p[j] = v * attv[j];
    }
    #pragma unroll
    for (int off = 32; off > 0; off >>= 1){
      p[0] += __shfl_xor(p[0], off, 64);
      p[1] += __shfl_xor(p[1], off, 64);
      p[2] += __shfl_xor(p[2], off, 64);
      p[3] += __shfl_xor(p[3], off, 64);
    }
    if (lane == 0){
      float4 o = make_float4(p[0], p[1], p[2], p[3]);
      *(float4*)(lgout + (size_t)pos*4) = o;
    }
  }
}

// ---------- per-node softmax + aggregation: sequential lg/csrc, 1 packed gather/edge ----------
__global__ __launch_bounds__(256)
void k_aggr(const int* __restrict__ row_ptr, const int* __restrict__ csrc,
            const float* __restrict__ lg, const ushort_t* __restrict__ xlh,
            const float* __restrict__ bias, const float* __restrict__ resid,
            float* __restrict__ out){
  int lane = threadIdx.x & 63;
  int n = blockIdx.x*4 + (threadIdx.x >> 6);
  if (n >= NN) return;
  int rr0 = row_ptr[n], rr1 = row_ptr[n+1];

  // pass 1: max (sequential lg)
  float m0=-3.4e38f, m1=m0, m2=m0, m3=m0;
  for (int idx = rr0 + lane; idx < rr1; idx += 64){
    float4 l = ld4(lg + (size_t)idx*4);
    m0 = fmaxf(m0, l.x); m1 = fmaxf(m1, l.y); m2 = fmaxf(m2, l.z); m3 = fmaxf(m3, l.w);
  }
  #pragma unroll
  for (int off = 32; off > 0; off >>= 1){
    m0 = fmaxf(m0, __shfl_xor(m0, off, 64));
    m1 = fmaxf(m1, __shfl_xor(m1, off, 64));
    m2 = fmaxf(m2, __shfl_xor(m2, off, 64));
    m3 = fmaxf(m3, __shfl_xor(m3, off, 64));
  }
  // pass 2: denom
  float d0=0.f, d1=0.f, d2=0.f, d3=0.f;
  for (int idx = rr0 + lane; idx < rr1; idx += 64){
    float4 l = ld4(lg + (size_t)idx*4);
    d0 += __expf(l.x - m0); d1 += __expf(l.y - m1);
    d2 += __expf(l.z - m2); d3 += __expf(l.w - m3);
  }
  #pragma unroll
  for (int off = 32; off > 0; off >>= 1){
    d0 += __shfl_xor(d0, off, 64); d1 += __shfl_xor(d1, off, 64);
    d2 += __shfl_xor(d2, off, 64); d3 += __shfl_xor(d3, off, 64);
  }
  float i0 = 1.0f/d0, i1 = 1.0f/d1, i2 = 1.0f/d2, i3 = 1.0f/d3;

  // pass 3: weighted packed-bf16 gather, 1 load/edge, pipelined 1 ahead
  float acc = 0.f;
  int sC = rfl(csrc[rr0]);
  float4 lC = ld4(lg + (size_t)rr0*4);
  uint2 xa = *(const uint2*)(xlh + (size_t)sC*HC + lane*4);

  for (int idx = rr0; idx < rr1; idx++){
    int sN = 0;
    float4 lN = make_float4(0.f,0.f,0.f,0.f);
    uint2 xb = make_uint2(0u, 0u);
    if (idx + 1 < rr1){
      sN = rfl(csrc[idx+1]);
      lN = ld4(lg + (size_t)(idx+1)*4);
      xb = *(const uint2*)(xlh + (size_t)sN*HC + lane*4);
    }
    float a0 = __expf(lC.x - m0)*i0;
    float a1 = __expf(lC.y - m1)*i1;
    float a2 = __expf(lC.z - m2)*i2;
    float a3 = __expf(lC.w - m3)*i3;
    acc += a0*b2f_lo(xa.x) + a1*b2f_hi(xa.x) + a2*b2f_lo(xa.y) + a3*b2f_hi(xa.y);
    sC = sN; lC = lN; xa = xb;
  }
  float val = acc*0.25f + bias[lane];
  if (resid) val += resid[(size_t)n*CC + lane];
  out[(size_t)n*CC + lane] = val;
}

extern "C" void kernel_launch(void* const* d_in, const int* in_sizes, int n_in,
                              void* d_out, int out_size, void* d_ws, size_t ws_size,
                              hipStream_t stream) {
  const float* x     = (const float*)d_in[0];
  const int*   ei    = (const int*)d_in[1];
  const int*   src   = ei;
  const int*   dst   = ei + EE;
  const float* ea    = (const float*)d_in[2];
  const int*   batch = (const int*)d_in[3];
  const float* Wl    = (const float*)d_in[4];
  const float* Wr    = (const float*)d_in[5];
  const float* We    = (const float*)d_in[6];
  const float* att   = (const float*)d_in[7];
  const float* gb    = (const float*)d_in[8];
  const float* gw    = (const float*)d_in[9];
  const float* gnb   = (const float*)d_in[10];
  const float* gms   = (const float*)d_in[11];
  float* out = (float*)d_out;

  char* ws = (char*)d_ws;
  size_t off = 0;
  auto alloc = [&](size_t bytes) -> void* {
    void* p = ws + off; off += (bytes + 255) & ~(size_t)255; return p;
  };
  int*   cnt     = (int*)alloc(NN*sizeof(int));
  int*   loc     = (int*)alloc(NN*sizeof(int));
  int*   bsum    = (int*)alloc(64*sizeof(int));
  int*   wp      = (int*)alloc(NN*sizeof(int));
  int*   row_ptr = (int*)alloc((NN+1)*sizeof(int));
  int*   epos    = (int*)alloc((size_t)ETOT*sizeof(int));
  int*   csrc    = (int*)alloc((size_t)ETOT*sizeof(int));
  float* easum   = (float*)alloc(64);
  float* hbuf    = (float*)alloc((size_t)NN*CC*sizeof(float));
  ushort_t* xlh  = (ushort_t*)alloc((size_t)NN*HC*sizeof(ushort_t));
  ushort_t* xrh  = (ushort_t*)alloc((size_t)NN*HC*sizeof(ushort_t));
  float* lgbuf   = (float*)alloc((size_t)ETOT*HH*sizeof(float));
  float* xbuf    = (float*)alloc((size_t)NN*CC*sizeof(float));
  if (off > ws_size) return;   // insufficient workspace -> fail loudly (no launch)

  hipMemsetAsync(cnt, 0, NN*sizeof(int), stream);
  hipMemsetAsync(easum, 0, 64, stream);
  k_easum<<<1024, 256, 0, stream>>>(ea, easum);
  k_hist<<<(ETOT+255)/256, 256, 0, stream>>>(dst, cnt);
  k_scan1<<<NB, 1024, 0, stream>>>(cnt, loc, bsum);
  k_scan2<<<1, 64, 0, stream>>>(bsum, row_ptr);
  k_scan3<<<NB, 1024, 0, stream>>>(loc, bsum, row_ptr, wp);
  k_scatter<<<(ETOT+255)/256, 256, 0, stream>>>(dst, src, wp, epos, csrc);

  for (int i = 0; i < 2; i++){
    const float* xin = i ? xbuf : x;
    k_norm<<<NBATCH, 256, 0, stream>>>(xin, batch, gw + i*CC, gnb + i*CC, gms + i*CC, hbuf);
    k_gemm<<<dim3(NGB, 1, 2), 256, 0, stream>>>(hbuf, Wl + (size_t)i*CC*HC, Wr + (size_t)i*CC*HC, xlh, xrh);
    k_logits<<<2048, 256, 0, stream>>>(xlh, xrh, src, dst, epos, ea,
                                       We + (size_t)i*DEA*HC, att + i*HH*CC, lgbuf);
    k_logits_self<<<256, 256, 0, stream>>>(xlh, xrh, epos, easum,
                                           We + (size_t)i*DEA*HC, att + i*HH*CC, lgbuf);
    k_aggr<<<(NN+3)/4, 256, 0, stream>>>(row_ptr, csrc, lgbuf, xlh, gb + i*CC,
                                         i ? x : nullptr, i ? out : xbuf);
  }
}

// Round 6
// 807.058 us; speedup vs baseline: 1.3360x; 1.2446x over previous
//
#include <hip/hip_runtime.h>
#include <math.h>

#define NN 50000
#define EE 400000
#define ETOT 450000      // EE + NN self loops
#define CC 64
#define HH 4
#define DEA 16
#define NBATCH 64
#define HC 256           // HH*CC
#define EPSV 1e-5f
#define NB 49            // ceil(NN/1024)
#define NGB 782          // ceil(NN/64)

typedef unsigned short ushort_t;
typedef unsigned int uint_t;

__device__ __forceinline__ float4 ld4(const float* p){ return *(const float4*)p; }
__device__ __forceinline__ int rfl(int v){ return __builtin_amdgcn_readfirstlane(v); }
__device__ __forceinline__ ushort_t f2b(float f){
  uint_t u = __float_as_uint(f);
  uint_t r = (u + 0x7FFFu + ((u >> 16) & 1u)) >> 16;
  return (ushort_t)r;
}
// packed-pair bf16 -> float: low half / high half of a uint
__device__ __forceinline__ float b2f_lo(uint_t u){ return __uint_as_float(u << 16); }
__device__ __forceinline__ float b2f_hi(uint_t u){ return __uint_as_float(u & 0xFFFF0000u); }

// ---------- edge_attr column sums (for self-loop mean fill) ----------
__global__ void k_easum(const float* __restrict__ ea, float* __restrict__ easum){
  int tid = threadIdx.x;
  int gid = blockIdx.x*256 + tid;
  int gsz = gridDim.x*256;              // multiple of 16 -> col stable
  float s = 0.f;
  for (long long i = gid; i < (long long)EE*DEA; i += gsz) s += ea[i];
  __shared__ float sd[256];
  sd[tid] = s; __syncthreads();
  if (tid < DEA){
    float t = 0.f;
    for (int j = tid; j < 256; j += DEA) t += sd[j];
    atomicAdd(&easum[tid], t);
  }
}

// ---------- CSR build ----------
__global__ void k_hist(const int* __restrict__ dst, int* __restrict__ cnt){
  int e = blockIdx.x*256 + threadIdx.x;
  if (e < ETOT){
    int d = (e < EE) ? dst[e] : (e - EE);
    atomicAdd(&cnt[d], 1);
  }
}

__global__ __launch_bounds__(1024)
void k_scan1(const int* __restrict__ cnt, int* __restrict__ loc, int* __restrict__ bsum){
  __shared__ int wsum[16];
  int tid = threadIdx.x, lane = tid & 63, wv = tid >> 6;
  int i = blockIdx.x*1024 + tid;
  int v = (i < NN) ? cnt[i] : 0;
  int incl = v;
  #pragma unroll
  for (int off = 1; off < 64; off <<= 1){
    int t = __shfl_up(incl, off, 64);
    if (lane >= off) incl += t;
  }
  if (lane == 63) wsum[wv] = incl;
  __syncthreads();
  if (wv == 0){
    int s = (lane < 16) ? wsum[lane] : 0;
    #pragma unroll
    for (int off = 1; off < 16; off <<= 1){
      int t = __shfl_up(s, off, 64);
      if (lane >= off) s += t;
    }
    if (lane < 16) wsum[lane] = s;
  }
  __syncthreads();
  int excl = (wv ? wsum[wv-1] : 0) + incl - v;
  if (i < NN) loc[i] = excl;
  if (tid == 1023) bsum[blockIdx.x] = wsum[15];
}

__global__ void k_scan2(int* __restrict__ bsum, int* __restrict__ row_ptr){
  int lane = threadIdx.x;   // 64 threads
  int v = (lane < NB) ? bsum[lane] : 0;
  int incl = v;
  #pragma unroll
  for (int off = 1; off < 64; off <<= 1){
    int t = __shfl_up(incl, off, 64);
    if (lane >= off) incl += t;
  }
  if (lane < NB) bsum[lane] = incl - v;
  if (lane == 63) row_ptr[NN] = incl;
}

__global__ __launch_bounds__(1024)
void k_scan3(const int* __restrict__ loc, const int* __restrict__ bsum,
             int* __restrict__ row_ptr, int* __restrict__ wp){
  int i = blockIdx.x*1024 + threadIdx.x;
  if (i < NN){
    int v = loc[i] + bsum[blockIdx.x];
    row_ptr[i] = v; wp[i] = v;
  }
}

// scatter: epos[e] = CSR slot of edge e; csrc[slot] = src node of that edge
__global__ void k_scatter(const int* __restrict__ dst, const int* __restrict__ src,
                          int* __restrict__ wp, int* __restrict__ epos, int* __restrict__ csrc){
  int e = blockIdx.x*256 + threadIdx.x;
  if (e < ETOT){
    int d, s;
    if (e < EE){ d = dst[e]; s = src[e]; } else { d = e - EE; s = d; }
    int pos = atomicAdd(&wp[d], 1);
    epos[e] = pos;
    csrc[pos] = s;
  }
}

// ---------- pack W (both layers, both mats) into head-interleaved bf16 [k][c*4+h] ----------
__global__ void k_packw(const float* __restrict__ Wl, const float* __restrict__ Wr,
                        ushort_t* __restrict__ Wp){
  int t = blockIdx.x*256 + threadIdx.x;   // 2*2*64*64 = 16384
  if (t >= 16384) return;
  int c = t & 63;
  int k = (t >> 6) & 63;
  int mat = (t >> 12) & 1;
  int l = t >> 13;
  const float* W = (mat ? Wr : Wl) + (size_t)l*CC*HC;
  float w0 = W[(size_t)k*HC + 0*64 + c];
  float w1 = W[(size_t)k*HC + 1*64 + c];
  float w2 = W[(size_t)k*HC + 2*64 + c];
  float w3 = W[(size_t)k*HC + 3*64 + c];
  uint2 o;
  o.x = (uint_t)f2b(w0) | ((uint_t)f2b(w1) << 16);
  o.y = (uint_t)f2b(w2) | ((uint_t)f2b(w3) << 16);
  *(uint2*)(Wp + ((size_t)((l*2+mat)*64 + k))*HC + c*4) = o;
}

// ---------- GraphNorm stats: one full-BW pass, per-(batch,channel) sum & sumsq ----------
// batch is sorted; accumulate in registers over runs, atomics only at transitions.
__global__ __launch_bounds__(256)
void k_stats(const float* __restrict__ x, const int* __restrict__ batch,
             float* __restrict__ S, float* __restrict__ Q){
  int c = threadIdx.x & 63, g = threadIdx.x >> 6;
  int r0 = blockIdx.x*256;
  int hiR = r0 + 256; if (hiR > NN) hiR = NN;
  float s = 0.f, q = 0.f;
  int curb = -1;
  for (int n = r0 + g; n < hiR; n += 4){
    int b = batch[n];
    if (b != curb){
      if (curb >= 0){ atomicAdd(&S[curb*64+c], s); atomicAdd(&Q[curb*64+c], q); }
      curb = b; s = 0.f; q = 0.f;
    }
    float v = x[(size_t)n*CC + c];
    s += v; q += v*v;
  }
  if (curb >= 0){ atomicAdd(&S[curb*64+c], s); atomicAdd(&Q[curb*64+c], q); }
}

__device__ __forceinline__ int lowerb(const int* a, int n, int key){
  int lo = 0, hi = n;
  while (lo < hi){ int mid = (lo+hi) >> 1; if (a[mid] < key) lo = mid+1; else hi = mid; }
  return lo;
}

// ---------- fold stats to per-(batch,channel) scale/shift ----------
__global__ void k_fin(const float* __restrict__ S, const float* __restrict__ Q,
                      const int* __restrict__ batch,
                      const float* __restrict__ w, const float* __restrict__ bb,
                      const float* __restrict__ ms,
                      float* __restrict__ scale, float* __restrict__ shift){
  __shared__ float cntf;
  int b = blockIdx.x, c = threadIdx.x;   // 64 x 64
  if (c == 0){
    int lo = lowerb(batch, NN, b), hi = lowerb(batch, NN, b+1);
    cntf = fmaxf((float)(hi - lo), 1.f);
  }
  __syncthreads();
  float inv = 1.f / cntf;
  float m = S[b*64+c] * inv;
  float a = ms[c] * m;
  float var = Q[b*64+c]*inv - 2.f*a*m + a*a;   // E[(x-a)^2]
  var = fmaxf(var, 0.f);
  float rstd = rsqrtf(var + EPSV);
  float sc = rstd * w[c];
  scale[b*64+c] = sc;
  shift[b*64+c] = bb[c] - a*sc;
}

// ---------- GEMM with fused GraphNorm+ReLU on input: [N,64] @ [64,256] -> bf16 packed ----------
// hT staging applies h = max(x*scale+shift, 0). Weights from packed bf16 Wp (global, L1-hot).
__global__ __launch_bounds__(256)
void k_gemm(const float* __restrict__ x, const int* __restrict__ batch,
            const float* __restrict__ scale, const float* __restrict__ shift,
            const ushort_t* __restrict__ WpA, const ushort_t* __restrict__ WpB,
            ushort_t* __restrict__ outA, ushort_t* __restrict__ outB){
  const ushort_t* Wp = blockIdx.z ? WpB : WpA;
  ushort_t* out = blockIdx.z ? outB : outA;
  int n0 = blockIdx.x * 64;
  __shared__ float hT[64][72];      // [k][row]
  int tid = threadIdx.x;
  for (int t = tid; t < 1024; t += 256){      // 64 rows x 16 float4
    int r = t >> 4, ch = t & 15;
    int n = n0 + r;
    float4 v = make_float4(0.f,0.f,0.f,0.f);
    if (n < NN){
      int b = batch[n];
      v = ld4(x + (size_t)n*CC + ch*4);
      float4 sc = ld4(scale + b*64 + ch*4);
      float4 sh = ld4(shift + b*64 + ch*4);
      v.x = fmaxf(v.x*sc.x + sh.x, 0.f);
      v.y = fmaxf(v.y*sc.y + sh.y, 0.f);
      v.z = fmaxf(v.z*sc.z + sh.z, 0.f);
      v.w = fmaxf(v.w*sc.w + sh.w, 0.f);
    }
    hT[ch*4+0][r] = v.x; hT[ch*4+1][r] = v.y; hT[ch*4+2][r] = v.z; hT[ch*4+3][r] = v.w;
  }
  __syncthreads();
  int c = tid & 63, rg = tid >> 6;
  int r0 = rg * 16;
  float acc[16][4];
  #pragma unroll
  for (int i = 0; i < 16; i++){ acc[i][0]=0.f; acc[i][1]=0.f; acc[i][2]=0.f; acc[i][3]=0.f; }
  #pragma unroll 4
  for (int k = 0; k < 64; k++){
    float4 a0 = *(const float4*)&hT[k][r0+0];
    float4 a1 = *(const float4*)&hT[k][r0+4];
    float4 a2 = *(const float4*)&hT[k][r0+8];
    float4 a3 = *(const float4*)&hT[k][r0+12];
    uint2 wv = *(const uint2*)(Wp + (size_t)k*HC + c*4);
    float b0 = b2f_lo(wv.x), b1 = b2f_hi(wv.x), b2 = b2f_lo(wv.y), b3 = b2f_hi(wv.y);
    const float av[16] = {a0.x,a0.y,a0.z,a0.w, a1.x,a1.y,a1.z,a1.w,
                          a2.x,a2.y,a2.z,a2.w, a3.x,a3.y,a3.z,a3.w};
    #pragma unroll
    for (int i = 0; i < 16; i++){
      acc[i][0] += av[i]*b0; acc[i][1] += av[i]*b1;
      acc[i][2] += av[i]*b2; acc[i][3] += av[i]*b3;
    }
  }
  #pragma unroll
  for (int i = 0; i < 16; i++){
    int n = n0 + r0 + i;
    if (n < NN){
      uint2 o;
      o.x = (uint_t)f2b(acc[i][0]) | ((uint_t)f2b(acc[i][1]) << 16);
      o.y = (uint_t)f2b(acc[i][2]) | ((uint_t)f2b(acc[i][3]) << 16);
      *(uint2*)(out + (size_t)n*HC + c*4) = o;
    }
  }
}

// ---------- per-edge logits, edge order, packed gathers, scalarized indices ----------
__global__ __launch_bounds__(256)
void k_logits(const ushort_t* __restrict__ xlh, const ushort_t* __restrict__ xrh,
              const int* __restrict__ src, const int* __restrict__ dst,
              const int* __restrict__ epos,
              const float* __restrict__ ea,
              const float* __restrict__ We, const float* __restrict__ att,
              float* __restrict__ lgout){
  int lane = threadIdx.x & 63;
  int gwid = (blockIdx.x*256 + threadIdx.x) >> 6;
  int nw = (gridDim.x*256) >> 6;
  float wer[4][16];
  #pragma unroll
  for (int j = 0; j < 4; j++)
    #pragma unroll
    for (int k = 0; k < 16; k++)
      wer[j][k] = We[(size_t)k*HC + j*64 + lane];
  float attv[4];
  #pragma unroll
  for (int j = 0; j < 4; j++) attv[j] = att[j*64 + lane];

  auto body = [&](int e){
    int eu = rfl(e);
    int s = src[eu], d = dst[eu], pos = epos[eu];   // uniform -> s_load
    uint2 xlp = *(const uint2*)(xlh + (size_t)s*HC + lane*4);
    uint2 xrp = *(const uint2*)(xrh + (size_t)d*HC + lane*4);
    float4 e0 = ld4(ea + (size_t)eu*DEA + 0);
    float4 e1 = ld4(ea + (size_t)eu*DEA + 4);
    float4 e2 = ld4(ea + (size_t)eu*DEA + 8);
    float4 e3 = ld4(ea + (size_t)eu*DEA + 12);
    const float ear[16] = {e0.x,e0.y,e0.z,e0.w, e1.x,e1.y,e1.z,e1.w,
                           e2.x,e2.y,e2.z,e2.w, e3.x,e3.y,e3.z,e3.w};
    float xlf[4] = {b2f_lo(xlp.x), b2f_hi(xlp.x), b2f_lo(xlp.y), b2f_hi(xlp.y)};
    float xrf[4] = {b2f_lo(xrp.x), b2f_hi(xrp.x), b2f_lo(xrp.y), b2f_hi(xrp.y)};
    float p[4];
    #pragma unroll
    for (int j = 0; j < 4; j++){
      float eev = 0.f;
      #pragma unroll
      for (int k = 0; k < 16; k++) eev += ear[k]*wer[j][k];
      float v = xlf[j] + xrf[j] + eev;
      v = (v > 0.f) ? v : 0.2f*v;
      p[j] = v * attv[j];
    }
    #pragma unroll
    for (int off = 32; off > 0; off >>= 1){
      p[0] += __shfl_xor(p[0], off, 64);
      p[1] += __shfl_xor(p[1], off, 64);
      p[2] += __shfl_xor(p[2], off, 64);
      p[3] += __shfl_xor(p[3], off, 64);
    }
    if (lane == 0){
      float4 o = make_float4(p[0], p[1], p[2], p[3]);
      *(float4*)(lgout + (size_t)pos*4) = o;
    }
  };

  for (int e = gwid; e < EE; e += 2*nw){
    body(e);
    int e2 = e + nw;
    if (e2 < EE) body(e2);
  }
}

// ---------- self-loop logits: sequential rows, no gathers ----------
__global__ __launch_bounds__(256)
void k_logits_self(const ushort_t* __restrict__ xlh, const ushort_t* __restrict__ xrh,
                   const int* __restrict__ epos, const float* __restrict__ easum,
                   const float* __restrict__ We, const float* __restrict__ att,
                   float* __restrict__ lgout){
  int lane = threadIdx.x & 63;
  int gwid = (blockIdx.x*256 + threadIdx.x) >> 6;
  int nw = (gridDim.x*256) >> 6;
  float attv[4], selfv[4];
  #pragma unroll
  for (int j = 0; j < 4; j++) attv[j] = att[j*64 + lane];
  {
    const float invE = 1.0f / (float)EE;
    #pragma unroll
    for (int j = 0; j < 4; j++){
      float t = 0.f;
      #pragma unroll
      for (int k = 0; k < 16; k++) t += (easum[k]*invE)*We[(size_t)k*HC + j*64 + lane];
      selfv[j] = t;
    }
  }
  for (int n = gwid; n < NN; n += nw){
    int nu = rfl(n);
    int pos = epos[EE + nu];                 // uniform -> s_load
    uint2 xlp = *(const uint2*)(xlh + (size_t)nu*HC + lane*4);
    uint2 xrp = *(const uint2*)(xrh + (size_t)nu*HC + lane*4);
    float p[4] = {b2f_lo(xlp.x)+b2f_lo(xrp.x)+selfv[0], b2f_hi(xlp.x)+b2f_hi(xrp.x)+selfv[1],
                  b2f_lo(xlp.y)+b2f_lo(xrp.y)+selfv[2], b2f_hi(xlp.y)+b2f_hi(xrp.y)+selfv[3]};
    #pragma unroll
    for (int j = 0; j < 4; j++){
      float v = p[j];
      v = (v > 0.f) ? v : 0.2f*v;
      p[j] = v * attv[j];
    }
    #pragma unroll
    for (int off = 32; off > 0; off >>= 1){
      p[0] += __shfl_xor(p[0], off, 64);
      p[1] += __shfl_xor(p[1], off, 64);
      p[2] += __shfl_xor(p[2], off, 64);
      p[3] += __shfl_xor(p[3], off, 64);
    }
    if (lane == 0){
      float4 o = make_float4(p[0], p[1], p[2], p[3]);
      *(float4*)(lgout + (size_t)pos*4) = o;
    }
  }
}

// ---------- per-node softmax + aggregation: sequential lg/csrc, 1 packed gather/edge ----------
__global__ __launch_bounds__(256)
void k_aggr(const int* __restrict__ row_ptr, const int* __restrict__ csrc,
            const float* __restrict__ lg, const ushort_t* __restrict__ xlh,
            const float* __restrict__ bias, const float* __restrict__ resid,
            float* __restrict__ out){
  int lane = threadIdx.x & 63;
  int n = blockIdx.x*4 + (threadIdx.x >> 6);
  if (n >= NN) return;
  int rr0 = row_ptr[n], rr1 = row_ptr[n+1];

  // pass 1: max (sequential lg)
  float m0=-3.4e38f, m1=m0, m2=m0, m3=m0;
  for (int idx = rr0 + lane; idx < rr1; idx += 64){
    float4 l = ld4(lg + (size_t)idx*4);
    m0 = fmaxf(m0, l.x); m1 = fmaxf(m1, l.y); m2 = fmaxf(m2, l.z); m3 = fmaxf(m3, l.w);
  }
  #pragma unroll
  for (int off = 32; off > 0; off >>= 1){
    m0 = fmaxf(m0, __shfl_xor(m0, off, 64));
    m1 = fmaxf(m1, __shfl_xor(m1, off, 64));
    m2 = fmaxf(m2, __shfl_xor(m2, off, 64));
    m3 = fmaxf(m3, __shfl_xor(m3, off, 64));
  }
  // pass 2: denom
  float d0=0.f, d1=0.f, d2=0.f, d3=0.f;
  for (int idx = rr0 + lane; idx < rr1; idx += 64){
    float4 l = ld4(lg + (size_t)idx*4);
    d0 += __expf(l.x - m0); d1 += __expf(l.y - m1);
    d2 += __expf(l.z - m2); d3 += __expf(l.w - m3);
  }
  #pragma unroll
  for (int off = 32; off > 0; off >>= 1){
    d0 += __shfl_xor(d0, off, 64); d1 += __shfl_xor(d1, off, 64);
    d2 += __shfl_xor(d2, off, 64); d3 += __shfl_xor(d3, off, 64);
  }
  float i0 = 1.0f/d0, i1 = 1.0f/d1, i2 = 1.0f/d2, i3 = 1.0f/d3;

  // pass 3: weighted packed-bf16 gather, 1 load/edge, pipelined 1 ahead
  float acc = 0.f;
  int sC = rfl(csrc[rr0]);
  float4 lC = ld4(lg + (size_t)rr0*4);
  uint2 xa = *(const uint2*)(xlh + (size_t)sC*HC + lane*4);

  for (int idx = rr0; idx < rr1; idx++){
    int sN = 0;
    float4 lN = make_float4(0.f,0.f,0.f,0.f);
    uint2 xb = make_uint2(0u, 0u);
    if (idx + 1 < rr1){
      sN = rfl(csrc[idx+1]);
      lN = ld4(lg + (size_t)(idx+1)*4);
      xb = *(const uint2*)(xlh + (size_t)sN*HC + lane*4);
    }
    float a0 = __expf(lC.x - m0)*i0;
    float a1 = __expf(lC.y - m1)*i1;
    float a2 = __expf(lC.z - m2)*i2;
    float a3 = __expf(lC.w - m3)*i3;
    acc += a0*b2f_lo(xa.x) + a1*b2f_hi(xa.x) + a2*b2f_lo(xa.y) + a3*b2f_hi(xa.y);
    sC = sN; lC = lN; xa = xb;
  }
  float val = acc*0.25f + bias[lane];
  if (resid) val += resid[(size_t)n*CC + lane];
  out[(size_t)n*CC + lane] = val;
}

extern "C" void kernel_launch(void* const* d_in, const int* in_sizes, int n_in,
                              void* d_out, int out_size, void* d_ws, size_t ws_size,
                              hipStream_t stream) {
  const float* x     = (const float*)d_in[0];
  const int*   ei    = (const int*)d_in[1];
  const int*   src   = ei;
  const int*   dst   = ei + EE;
  const float* ea    = (const float*)d_in[2];
  const int*   batch = (const int*)d_in[3];
  const float* Wl    = (const float*)d_in[4];
  const float* Wr    = (const float*)d_in[5];
  const float* We    = (const float*)d_in[6];
  const float* att   = (const float*)d_in[7];
  const float* gb    = (const float*)d_in[8];
  const float* gw    = (const float*)d_in[9];
  const float* gnb   = (const float*)d_in[10];
  const float* gms   = (const float*)d_in[11];
  float* out = (float*)d_out;

  char* ws = (char*)d_ws;
  size_t off = 0;
  auto alloc = [&](size_t bytes) -> void* {
    void* p = ws + off; off += (bytes + 255) & ~(size_t)255; return p;
  };
  int*   cnt     = (int*)alloc(NN*sizeof(int));
  int*   loc     = (int*)alloc(NN*sizeof(int));
  int*   bsum    = (int*)alloc(64*sizeof(int));
  int*   wp      = (int*)alloc(NN*sizeof(int));
  int*   row_ptr = (int*)alloc((NN+1)*sizeof(int));
  int*   epos    = (int*)alloc((size_t)ETOT*sizeof(int));
  int*   csrc    = (int*)alloc((size_t)ETOT*sizeof(int));
  float* easum   = (float*)alloc(64);
  float* statSQ  = (float*)alloc(4*4096*sizeof(float));   // S[2][4096], Q[2][4096]
  float* scaleb  = (float*)alloc(4096*sizeof(float));
  float* shiftb  = (float*)alloc(4096*sizeof(float));
  ushort_t* Wp   = (ushort_t*)alloc((size_t)4*64*HC*sizeof(ushort_t));  // [layer][mat][k][256]
  ushort_t* xlh  = (ushort_t*)alloc((size_t)NN*HC*sizeof(ushort_t));
  ushort_t* xrh  = (ushort_t*)alloc((size_t)NN*HC*sizeof(ushort_t));
  float* lgbuf   = (float*)alloc((size_t)ETOT*HH*sizeof(float));
  float* xbuf    = (float*)alloc((size_t)NN*CC*sizeof(float));
  if (off > ws_size) return;   // insufficient workspace -> fail loudly (no launch)

  hipMemsetAsync(cnt, 0, NN*sizeof(int), stream);
  hipMemsetAsync(easum, 0, 64, stream);
  hipMemsetAsync(statSQ, 0, 4*4096*sizeof(float), stream);
  k_easum<<<1024, 256, 0, stream>>>(ea, easum);
  k_hist<<<(ETOT+255)/256, 256, 0, stream>>>(dst, cnt);
  k_scan1<<<NB, 1024, 0, stream>>>(cnt, loc, bsum);
  k_scan2<<<1, 64, 0, stream>>>(bsum, row_ptr);
  k_scan3<<<NB, 1024, 0, stream>>>(loc, bsum, row_ptr, wp);
  k_scatter<<<(ETOT+255)/256, 256, 0, stream>>>(dst, src, wp, epos, csrc);
  k_packw<<<64, 256, 0, stream>>>(Wl, Wr, Wp);

  for (int i = 0; i < 2; i++){
    const float* xin = i ? xbuf : x;
    float* S = statSQ + i*4096;
    float* Q = statSQ + 2*4096 + i*4096;
    k_stats<<<(NN+255)/256, 256, 0, stream>>>(xin, batch, S, Q);
    k_fin<<<64, 64, 0, stream>>>(S, Q, batch, gw + i*CC, gnb + i*CC, gms + i*CC, scaleb, shiftb);
    k_gemm<<<dim3(NGB, 1, 2), 256, 0, stream>>>(xin, batch, scaleb, shiftb,
                                                Wp + (size_t)(i*2+0)*64*HC,
                                                Wp + (size_t)(i*2+1)*64*HC,
                                                xlh, xrh);
    k_logits<<<2048, 256, 0, stream>>>(xlh, xrh, src, dst, epos, ea,
                                       We + (size_t)i*DEA*HC, att + i*HH*CC, lgbuf);
    k_logits_self<<<256, 256, 0, stream>>>(xlh, xrh, epos, easum,
                                           We + (size_t)i*DEA*HC, att + i*HH*CC, lgbuf);
    k_aggr<<<(NN+3)/4, 256, 0, stream>>>(row_ptr, csrc, lgbuf, xlh, gb + i*CC,
                                         i ? x : nullptr, i ? out : xbuf);
  }
}

// Round 7
// 500.468 us; speedup vs baseline: 2.1544x; 1.6126x over previous
//
#include <hip/hip_runtime.h>
#include <math.h>

#define NN 50000
#define EE 400000
#define ETOT 450000      // EE + NN self loops
#define CC 64
#define HH 4
#define DEA 16
#define NBATCH 64
#define HC 256           // HH*CC
#define EPSV 1e-5f
#define NB 49            // ceil(NN/1024)
#define NGB 782          // ceil(NN/64)
#define NPW 8            // nodes per wave in k_gat

typedef unsigned short ushort_t;
typedef unsigned int uint_t;

__device__ __forceinline__ float4 ld4(const float* p){ return *(const float4*)p; }
__device__ __forceinline__ int rfl(int v){ return __builtin_amdgcn_readfirstlane(v); }
__device__ __forceinline__ ushort_t f2b(float f){
  uint_t u = __float_as_uint(f);
  uint_t r = (u + 0x7FFFu + ((u >> 16) & 1u)) >> 16;
  return (ushort_t)r;
}
// packed-pair bf16 -> float: low half / high half of a uint
__device__ __forceinline__ float b2f_lo(uint_t u){ return __uint_as_float(u << 16); }
__device__ __forceinline__ float b2f_hi(uint_t u){ return __uint_as_float(u & 0xFFFF0000u); }

// ---------- edge_attr column sums (for self-loop mean fill) ----------
__global__ void k_easum(const float* __restrict__ ea, float* __restrict__ easum){
  int tid = threadIdx.x;
  int gid = blockIdx.x*256 + tid;
  int gsz = gridDim.x*256;              // multiple of 16 -> col stable
  float s = 0.f;
  for (long long i = gid; i < (long long)EE*DEA; i += gsz) s += ea[i];
  __shared__ float sd[256];
  sd[tid] = s; __syncthreads();
  if (tid < DEA){
    float t = 0.f;
    for (int j = tid; j < 256; j += DEA) t += sd[j];
    atomicAdd(&easum[tid], t);
  }
}

// ---------- CSR build ----------
__global__ void k_hist(const int* __restrict__ dst, int* __restrict__ cnt){
  int e = blockIdx.x*256 + threadIdx.x;
  if (e < ETOT){
    int d = (e < EE) ? dst[e] : (e - EE);
    atomicAdd(&cnt[d], 1);
  }
}

__global__ __launch_bounds__(1024)
void k_scan1(const int* __restrict__ cnt, int* __restrict__ loc, int* __restrict__ bsum){
  __shared__ int wsum[16];
  int tid = threadIdx.x, lane = tid & 63, wv = tid >> 6;
  int i = blockIdx.x*1024 + tid;
  int v = (i < NN) ? cnt[i] : 0;
  int incl = v;
  #pragma unroll
  for (int off = 1; off < 64; off <<= 1){
    int t = __shfl_up(incl, off, 64);
    if (lane >= off) incl += t;
  }
  if (lane == 63) wsum[wv] = incl;
  __syncthreads();
  if (wv == 0){
    int s = (lane < 16) ? wsum[lane] : 0;
    #pragma unroll
    for (int off = 1; off < 16; off <<= 1){
      int t = __shfl_up(s, off, 64);
      if (lane >= off) s += t;
    }
    if (lane < 16) wsum[lane] = s;
  }
  __syncthreads();
  int excl = (wv ? wsum[wv-1] : 0) + incl - v;
  if (i < NN) loc[i] = excl;
  if (tid == 1023) bsum[blockIdx.x] = wsum[15];
}

__global__ void k_scan2(int* __restrict__ bsum, int* __restrict__ row_ptr){
  int lane = threadIdx.x;   // 64 threads
  int v = (lane < NB) ? bsum[lane] : 0;
  int incl = v;
  #pragma unroll
  for (int off = 1; off < 64; off <<= 1){
    int t = __shfl_up(incl, off, 64);
    if (lane >= off) incl += t;
  }
  if (lane < NB) bsum[lane] = incl - v;
  if (lane == 63) row_ptr[NN] = incl;
}

__global__ __launch_bounds__(1024)
void k_scan3(const int* __restrict__ loc, const int* __restrict__ bsum,
             int* __restrict__ row_ptr, int* __restrict__ wp){
  int i = blockIdx.x*1024 + threadIdx.x;
  if (i < NN){
    int v = loc[i] + bsum[blockIdx.x];
    row_ptr[i] = v; wp[i] = v;
  }
}

// scatter: csrc[slot] = src node; eas[slot][16] = edge_attr (mean-filled for self loops)
__global__ void k_scatter(const int* __restrict__ dst, const int* __restrict__ src,
                          const float* __restrict__ ea, const float* __restrict__ easum,
                          int* __restrict__ wp, int* __restrict__ csrc,
                          float* __restrict__ eas){
  int e = blockIdx.x*256 + threadIdx.x;
  if (e >= ETOT) return;
  int d, s;
  if (e < EE){ d = dst[e]; s = src[e]; } else { d = e - EE; s = d; }
  int pos = atomicAdd(&wp[d], 1);
  csrc[pos] = s;
  float buf[16];
  if (e < EE){
    #pragma unroll
    for (int q = 0; q < 4; q++){
      float4 v = ld4(ea + (size_t)e*DEA + q*4);
      buf[q*4+0]=v.x; buf[q*4+1]=v.y; buf[q*4+2]=v.z; buf[q*4+3]=v.w;
    }
  } else {
    const float invE = 1.0f / (float)EE;
    #pragma unroll
    for (int k = 0; k < 16; k++) buf[k] = easum[k]*invE;
  }
  #pragma unroll
  for (int q = 0; q < 4; q++)
    *(float4*)(eas + (size_t)pos*DEA + q*4) =
      make_float4(buf[q*4+0], buf[q*4+1], buf[q*4+2], buf[q*4+3]);
}

// ---------- pack W (both layers, both mats) into bf16 [k][col] (original col order) ----------
__global__ void k_packw(const float* __restrict__ Wl, const float* __restrict__ Wr,
                        ushort_t* __restrict__ Wp){
  int t = blockIdx.x*256 + threadIdx.x;   // 2*2*64*64 = 16384, 4 cols each
  if (t >= 16384) return;
  int c4 = (t & 63) * 4;
  int k = (t >> 6) & 63;
  int mat = (t >> 12) & 1;
  int l = t >> 13;
  const float* W = (mat ? Wr : Wl) + (size_t)l*CC*HC;
  float4 w = ld4(W + (size_t)k*HC + c4);
  uint2 o;
  o.x = (uint_t)f2b(w.x) | ((uint_t)f2b(w.y) << 16);
  o.y = (uint_t)f2b(w.z) | ((uint_t)f2b(w.w) << 16);
  *(uint2*)(Wp + ((size_t)((l*2+mat)*64 + k))*HC + c4) = o;
}

// ---------- GraphNorm stats: per-(batch,channel) sum & sumsq (sorted batch, run-local acc) ----------
__global__ __launch_bounds__(256)
void k_stats(const float* __restrict__ x, const int* __restrict__ batch,
             float* __restrict__ S, float* __restrict__ Q){
  int c = threadIdx.x & 63, g = threadIdx.x >> 6;
  int r0 = blockIdx.x*256;
  int hiR = r0 + 256; if (hiR > NN) hiR = NN;
  float s = 0.f, q = 0.f;
  int curb = -1;
  for (int n = r0 + g; n < hiR; n += 4){
    int b = batch[n];
    if (b != curb){
      if (curb >= 0){ atomicAdd(&S[curb*64+c], s); atomicAdd(&Q[curb*64+c], q); }
      curb = b; s = 0.f; q = 0.f;
    }
    float v = x[(size_t)n*CC + c];
    s += v; q += v*v;
  }
  if (curb >= 0){ atomicAdd(&S[curb*64+c], s); atomicAdd(&Q[curb*64+c], q); }
}

__device__ __forceinline__ int lowerb(const int* a, int n, int key){
  int lo = 0, hi = n;
  while (lo < hi){ int mid = (lo+hi) >> 1; if (a[mid] < key) lo = mid+1; else hi = mid; }
  return lo;
}

// ---------- fold stats to per-(batch,channel) scale/shift ----------
__global__ void k_fin(const float* __restrict__ S, const float* __restrict__ Q,
                      const int* __restrict__ batch,
                      const float* __restrict__ w, const float* __restrict__ bb,
                      const float* __restrict__ ms,
                      float* __restrict__ scale, float* __restrict__ shift){
  __shared__ float cntf;
  int b = blockIdx.x, c = threadIdx.x;   // 64 x 64
  if (c == 0){
    int lo = lowerb(batch, NN, b), hi = lowerb(batch, NN, b+1);
    cntf = fmaxf((float)(hi - lo), 1.f);
  }
  __syncthreads();
  float inv = 1.f / cntf;
  float m = S[b*64+c] * inv;
  float a = ms[c] * m;
  float var = Q[b*64+c]*inv - 2.f*a*m + a*a;   // E[(x-a)^2]
  var = fmaxf(var, 0.f);
  float rstd = rsqrtf(var + EPSV);
  float sc = rstd * w[c];
  scale[b*64+c] = sc;
  shift[b*64+c] = bb[c] - a*sc;
}

// ---------- GEMM with fused GraphNorm+ReLU on input: [N,64] @ [64,256] -> bf16 head-major ----------
__global__ __launch_bounds__(256)
void k_gemm(const float* __restrict__ x, const int* __restrict__ batch,
            const float* __restrict__ scale, const float* __restrict__ shift,
            const ushort_t* __restrict__ WpA, const ushort_t* __restrict__ WpB,
            ushort_t* __restrict__ outA, ushort_t* __restrict__ outB){
  const ushort_t* Wp = blockIdx.z ? WpB : WpA;
  ushort_t* out = blockIdx.z ? outB : outA;
  int n0 = blockIdx.x * 64;
  __shared__ float hT[64][72];      // [k][row]
  int tid = threadIdx.x;
  for (int t = tid; t < 1024; t += 256){      // 64 rows x 16 float4
    int r = t >> 4, ch = t & 15;
    int n = n0 + r;
    float4 v = make_float4(0.f,0.f,0.f,0.f);
    if (n < NN){
      int b = batch[n];
      v = ld4(x + (size_t)n*CC + ch*4);
      float4 sc = ld4(scale + b*64 + ch*4);
      float4 sh = ld4(shift + b*64 + ch*4);
      v.x = fmaxf(v.x*sc.x + sh.x, 0.f);
      v.y = fmaxf(v.y*sc.y + sh.y, 0.f);
      v.z = fmaxf(v.z*sc.z + sh.z, 0.f);
      v.w = fmaxf(v.w*sc.w + sh.w, 0.f);
    }
    hT[ch*4+0][r] = v.x; hT[ch*4+1][r] = v.y; hT[ch*4+2][r] = v.z; hT[ch*4+3][r] = v.w;
  }
  __syncthreads();
  int c = tid & 63, rg = tid >> 6;
  int r0 = rg * 16;
  float acc[16][4];
  #pragma unroll
  for (int i = 0; i < 16; i++){ acc[i][0]=0.f; acc[i][1]=0.f; acc[i][2]=0.f; acc[i][3]=0.f; }
  #pragma unroll 4
  for (int k = 0; k < 64; k++){
    float4 a0 = *(const float4*)&hT[k][r0+0];
    float4 a1 = *(const float4*)&hT[k][r0+4];
    float4 a2 = *(const float4*)&hT[k][r0+8];
    float4 a3 = *(const float4*)&hT[k][r0+12];
    uint2 wv = *(const uint2*)(Wp + (size_t)k*HC + c*4);
    float b0 = b2f_lo(wv.x), b1 = b2f_hi(wv.x), b2 = b2f_lo(wv.y), b3 = b2f_hi(wv.y);
    const float av[16] = {a0.x,a0.y,a0.z,a0.w, a1.x,a1.y,a1.z,a1.w,
                          a2.x,a2.y,a2.z,a2.w, a3.x,a3.y,a3.z,a3.w};
    #pragma unroll
    for (int i = 0; i < 16; i++){
      acc[i][0] += av[i]*b0; acc[i][1] += av[i]*b1;
      acc[i][2] += av[i]*b2; acc[i][3] += av[i]*b3;
    }
  }
  #pragma unroll
  for (int i = 0; i < 16; i++){
    int n = n0 + r0 + i;
    if (n < NN){
      uint2 o;
      o.x = (uint_t)f2b(acc[i][0]) | ((uint_t)f2b(acc[i][1]) << 16);
      o.y = (uint_t)f2b(acc[i][2]) | ((uint_t)f2b(acc[i][3]) << 16);
      *(uint2*)(out + (size_t)n*HC + c*4) = o;
    }
  }
}

// ---------- FUSED GATv2: logits + online softmax + aggregation, one CSR pass ----------
// Wave layout: head h = lane>>4, channel group cg = lane&15 (4 channels/lane).
// Each wave owns NPW consecutive dst nodes. Per edge: ONE random row gather (xl),
// sequential csrc/eas (scalar loads), xr loaded once per node.
__global__ __launch_bounds__(256)
void k_gat(const int* __restrict__ row_ptr, const int* __restrict__ csrc,
           const float* __restrict__ eas,
           const ushort_t* __restrict__ xlh, const ushort_t* __restrict__ xrh,
           const float* __restrict__ We, const float* __restrict__ att,
           const float* __restrict__ bias, const float* __restrict__ resid,
           float* __restrict__ out){
  int lane = threadIdx.x & 63;
  int h = lane >> 4, cg = lane & 15;
  int col = h*64 + cg*4;
  int wid = (blockIdx.x*256 + threadIdx.x) >> 6;
  int n0 = wid * NPW;
  if (n0 >= NN) return;
  int n1 = n0 + NPW; if (n1 > NN) n1 = NN;

  // wer[q][k] = We[k][col+q]
  float wer[4][16];
  #pragma unroll
  for (int k = 0; k < 16; k++){
    float4 w = ld4(We + (size_t)k*HC + col);
    wer[0][k]=w.x; wer[1][k]=w.y; wer[2][k]=w.z; wer[3][k]=w.w;
  }
  float4 attv = ld4(att + col);
  float4 biasv = ld4(bias + cg*4);

  for (int n = n0; n < n1; n++){
    int rr0 = rfl(row_ptr[n]), rr1 = rfl(row_ptr[n+1]);
    uint2 xrp = *(const uint2*)(xrh + (size_t)n*HC + col);
    float xr0 = b2f_lo(xrp.x), xr1 = b2f_hi(xrp.x);
    float xr2 = b2f_lo(xrp.y), xr3 = b2f_hi(xrp.y);
    float m = -3.4e38f, dsum = 0.f;
    float a0 = 0.f, a1 = 0.f, a2 = 0.f, a3 = 0.f;

    int sC = rfl(csrc[rr0]);
    uint2 xlp = *(const uint2*)(xlh + (size_t)sC*HC + col);

    for (int idx = rr0; idx < rr1; idx++){
      // prefetch next edge's xl row (clamped index keeps it unconditional)
      int idn = (idx+1 < rr1) ? idx+1 : rr0;
      int sN = rfl(csrc[idn]);
      uint2 xlq = *(const uint2*)(xlh + (size_t)sN*HC + col);

      // unpack current xl
      float xl0 = b2f_lo(xlp.x), xl1 = b2f_hi(xlp.x);
      float xl2 = b2f_lo(xlp.y), xl3 = b2f_hi(xlp.y);

      // edge-attr term: uniform address -> scalar loads, SGPR operands in fmac
      const float* ep = eas + (size_t)rfl(idx)*DEA;
      float p0 = 0.f, p1 = 0.f, p2 = 0.f, p3 = 0.f;
      #pragma unroll
      for (int k = 0; k < 16; k++){
        float ek = ep[k];
        p0 += ek*wer[0][k]; p1 += ek*wer[1][k];
        p2 += ek*wer[2][k]; p3 += ek*wer[3][k];
      }
      float v0 = xl0 + xr0 + p0; v0 = (v0 > 0.f) ? v0 : 0.2f*v0;
      float v1 = xl1 + xr1 + p1; v1 = (v1 > 0.f) ? v1 : 0.2f*v1;
      float v2 = xl2 + xr2 + p2; v2 = (v2 > 0.f) ? v2 : 0.2f*v2;
      float v3 = xl3 + xr3 + p3; v3 = (v3 > 0.f) ? v3 : 0.2f*v3;
      float pl = v0*attv.x + v1*attv.y + v2*attv.z + v3*attv.w;
      // reduce over the 16 lanes of this head group
      #pragma unroll
      for (int off = 1; off < 16; off <<= 1) pl += __shfl_xor(pl, off, 16);

      // online softmax update
      float mn = fmaxf(m, pl);
      float sc = __expf(m - mn);
      float wexp = __expf(pl - mn);
      dsum = dsum*sc + wexp;
      a0 = a0*sc + wexp*xl0;
      a1 = a1*sc + wexp*xl1;
      a2 = a2*sc + wexp*xl2;
      a3 = a3*sc + wexp*xl3;
      m = mn;

      xlp = xlq;
    }

    float inv = 1.0f / dsum;
    float o0 = a0*inv, o1 = a1*inv, o2 = a2*inv, o3 = a3*inv;
    // sum across the 4 head groups (lanes differing in bits 4..5)
    #pragma unroll
    for (int off = 16; off < 64; off <<= 1){
      o0 += __shfl_xor(o0, off, 64);
      o1 += __shfl_xor(o1, off, 64);
      o2 += __shfl_xor(o2, off, 64);
      o3 += __shfl_xor(o3, off, 64);
    }
    if (lane < 16){
      float r0v = o0*0.25f + biasv.x;
      float r1v = o1*0.25f + biasv.y;
      float r2v = o2*0.25f + biasv.z;
      float r3v = o3*0.25f + biasv.w;
      if (resid){
        float4 rv = ld4(resid + (size_t)n*CC + cg*4);
        r0v += rv.x; r1v += rv.y; r2v += rv.z; r3v += rv.w;
      }
      *(float4*)(out + (size_t)n*CC + cg*4) = make_float4(r0v, r1v, r2v, r3v);
    }
  }
}

extern "C" void kernel_launch(void* const* d_in, const int* in_sizes, int n_in,
                              void* d_out, int out_size, void* d_ws, size_t ws_size,
                              hipStream_t stream) {
  const float* x     = (const float*)d_in[0];
  const int*   ei    = (const int*)d_in[1];
  const int*   src   = ei;
  const int*   dst   = ei + EE;
  const float* ea    = (const float*)d_in[2];
  const int*   batch = (const int*)d_in[3];
  const float* Wl    = (const float*)d_in[4];
  const float* Wr    = (const float*)d_in[5];
  const float* We    = (const float*)d_in[6];
  const float* att   = (const float*)d_in[7];
  const float* gb    = (const float*)d_in[8];
  const float* gw    = (const float*)d_in[9];
  const float* gnb   = (const float*)d_in[10];
  const float* gms   = (const float*)d_in[11];
  float* out = (float*)d_out;

  char* ws = (char*)d_ws;
  size_t off = 0;
  auto alloc = [&](size_t bytes) -> void* {
    void* p = ws + off; off += (bytes + 255) & ~(size_t)255; return p;
  };
  int*   cnt     = (int*)alloc(NN*sizeof(int));
  int*   loc     = (int*)alloc(NN*sizeof(int));
  int*   bsum    = (int*)alloc(64*sizeof(int));
  int*   wp      = (int*)alloc(NN*sizeof(int));
  int*   row_ptr = (int*)alloc((NN+1)*sizeof(int));
  int*   csrc    = (int*)alloc((size_t)ETOT*sizeof(int));
  float* eas     = (float*)alloc((size_t)ETOT*DEA*sizeof(float));
  float* easum   = (float*)alloc(64);
  float* statSQ  = (float*)alloc(4*4096*sizeof(float));   // S[2][4096], Q[2][4096]
  float* scaleb  = (float*)alloc(4096*sizeof(float));
  float* shiftb  = (float*)alloc(4096*sizeof(float));
  ushort_t* Wp   = (ushort_t*)alloc((size_t)4*64*HC*sizeof(ushort_t));  // [layer][mat][k][256]
  ushort_t* xlh  = (ushort_t*)alloc((size_t)NN*HC*sizeof(ushort_t));
  ushort_t* xrh  = (ushort_t*)alloc((size_t)NN*HC*sizeof(ushort_t));
  float* xbuf    = (float*)alloc((size_t)NN*CC*sizeof(float));
  if (off > ws_size) return;   // insufficient workspace -> fail loudly (no launch)

  hipMemsetAsync(cnt, 0, NN*sizeof(int), stream);
  hipMemsetAsync(easum, 0, 64, stream);
  hipMemsetAsync(statSQ, 0, 4*4096*sizeof(float), stream);
  k_easum<<<1024, 256, 0, stream>>>(ea, easum);
  k_hist<<<(ETOT+255)/256, 256, 0, stream>>>(dst, cnt);
  k_scan1<<<NB, 1024, 0, stream>>>(cnt, loc, bsum);
  k_scan2<<<1, 64, 0, stream>>>(bsum, row_ptr);
  k_scan3<<<NB, 1024, 0, stream>>>(loc, bsum, row_ptr, wp);
  k_scatter<<<(ETOT+255)/256, 256, 0, stream>>>(dst, src, ea, easum, wp, csrc, eas);
  k_packw<<<64, 256, 0, stream>>>(Wl, Wr, Wp);

  int gatBlocks = (NN + NPW*4 - 1) / (NPW*4);
  for (int i = 0; i < 2; i++){
    const float* xin = i ? xbuf : x;
    float* S = statSQ + i*4096;
    float* Q = statSQ + 2*4096 + i*4096;
    k_stats<<<(NN+255)/256, 256, 0, stream>>>(xin, batch, S, Q);
    k_fin<<<64, 64, 0, stream>>>(S, Q, batch, gw + i*CC, gnb + i*CC, gms + i*CC, scaleb, shiftb);
    k_gemm<<<dim3(NGB, 1, 2), 256, 0, stream>>>(xin, batch, scaleb, shiftb,
                                                Wp + (size_t)(i*2+0)*64*HC,
                                                Wp + (size_t)(i*2+1)*64*HC,
                                                xlh, xrh);
    k_gat<<<gatBlocks, 256, 0, stream>>>(row_ptr, csrc, eas, xlh, xrh,
                                         We + (size_t)i*DEA*HC, att + i*HH*CC,
                                         gb + i*CC, i ? x : nullptr, i ? out : xbuf);
  }
}